// Round 9
// baseline (944.017 us; speedup 1.0000x reference)
//
#include <hip/hip_runtime.h>
#include <hip/hip_fp16.h>
#include <math.h>

#define G_GRAPHS 8

// ---------- helpers ----------
__device__ __forceinline__ unsigned fmap(float f) {
    unsigned b = __float_as_uint(f);
    return (b & 0x80000000u) ? ~b : (b | 0x80000000u);
}
__device__ __forceinline__ float funmap(unsigned u) {
    unsigned b = (u & 0x80000000u) ? (u & 0x7fffffffu) : ~u;
    return __uint_as_float(b);
}
__device__ __forceinline__ void fma_row(float wv, uint2 r,
                                        float& ax, float& ay, float& az, float& aw) {
    float2 f01 = __half22float2(*(__half2*)&r.x);
    float2 f23 = __half22float2(*(__half2*)&r.y);
    ax += wv * f01.x; ay += wv * f01.y; az += wv * f23.x; aw += wv * f23.y;
}
__device__ __forceinline__ uint2 pack4(float ax, float ay, float az, float aw) {
    __half2 p01 = __float22half2_rn(make_float2(ax, ay));
    __half2 p23 = __float22half2_rn(make_float2(az, aw));
    uint2 r;
    r.x = *(unsigned*)&p01;
    r.y = *(unsigned*)&p23;
    return r;
}

// ---------- CSR build (self-loops folded in as edge 0 of each row) ----------
__global__ void k_count(const int* __restrict__ dst, int* __restrict__ deg, int E) {
    int e = blockIdx.x * 256 + threadIdx.x;
    if (e < E) atomicAdd(&deg[dst[e]], 1);
}

__global__ void k_dis(const int* __restrict__ deg, float* __restrict__ dis,
                      int* __restrict__ degp, int N) {
    int i = blockIdx.x * 256 + threadIdx.x;
    if (i < N) {
        int d = deg[i];
        dis[i] = rsqrtf((float)(d + 1));
        degp[i] = d + 1;                 // incl. self loop
    }
}

__global__ void k_scanA(const int* __restrict__ deg, int* __restrict__ rowst,
                        int* __restrict__ bsum, int N) {
    __shared__ int s[256];
    int i = blockIdx.x * 256 + threadIdx.x;
    int v = (i < N) ? deg[i] + 1 : 0;    // +1 self loop
    s[threadIdx.x] = v;
    __syncthreads();
    for (int off = 1; off < 256; off <<= 1) {
        int t = (threadIdx.x >= off) ? s[threadIdx.x - off] : 0;
        __syncthreads();
        s[threadIdx.x] += t;
        __syncthreads();
    }
    if (i < N) rowst[i] = s[threadIdx.x] - v;
    if (threadIdx.x == 255) bsum[blockIdx.x] = s[255];
}

__global__ void k_scanB(int* __restrict__ bsum, int NB) {
    __shared__ int s[512];
    int t = threadIdx.x;
    int v = (t < NB) ? bsum[t] : 0;
    s[t] = v;
    __syncthreads();
    for (int off = 1; off < 512; off <<= 1) {
        int x = (t >= off) ? s[t - off] : 0;
        __syncthreads();
        s[t] += x;
        __syncthreads();
    }
    if (t < NB) bsum[t] = s[t] - v;
}

__global__ void k_scanC(int* __restrict__ rowst, const int* __restrict__ bsum, int N) {
    int i = blockIdx.x * 256 + threadIdx.x;
    if (i < N) rowst[i] += bsum[blockIdx.x];
}

__global__ void k_self(const int* __restrict__ rowst, const int* __restrict__ deg,
                       int2* __restrict__ edge, int N) {
    int i = blockIdx.x * 256 + threadIdx.x;
    if (i < N) {
        float sw = 1.0f / (float)(deg[i] + 1);   // dis^2
        edge[rowst[i]] = make_int2(i, __float_as_int(sw));
    }
}

__global__ void k_fill(const int* __restrict__ src, const int* __restrict__ dst,
                       const float* __restrict__ dis, const int* __restrict__ rowst,
                       int* __restrict__ cnt, int2* __restrict__ edge, int E) {
    int e = blockIdx.x * 256 + threadIdx.x;
    if (e >= E) return;
    int d = dst[e], s = src[e];
    int p = rowst[d] + 1 + atomicAdd(&cnt[d], 1);   // slot 0 = self
    edge[p] = make_int2(s, __float_as_int(dis[s] * dis[d]));
}

// ---------- x -> fp16 ----------
__global__ void k_x2h(const float* __restrict__ x, __half* __restrict__ xh, int n4) {
    int i = blockIdx.x * 256 + threadIdx.x;
    if (i >= n4) return;
    float4 v = ((const float4*)x)[i];
    ((uint2*)xh)[i] = pack4(v.x, v.y, v.z, v.w);
}

// ---------- generic sliced prop over fp16 planes of 16 dims ----------
// plane layout: in/out + slice * N*16 halfs; slice = blockIdx & smask.
// wave: 2 nodes x 8 edge-groups x 4 lanes (8 B row-chunk each).
__global__ __launch_bounds__(256) void k_prop(
        const __half* __restrict__ in, __half* __restrict__ out,
        const int* __restrict__ rowst, const int* __restrict__ degp,
        const int2* __restrict__ edge,
        const float* __restrict__ bias, int relu, int N,
        int smask, int sshift) {
    int t = threadIdx.x, lane = t & 63, w = t >> 6;
    int sub = lane & 3, eg = (lane >> 2) & 7, n2 = lane >> 5;
    int slice = blockIdx.x & smask;
    int sbid = blockIdx.x >> sshift;
    int nslots = (gridDim.x >> sshift) * 4;
    size_t NP16 = (size_t)N * 16;
    const __half* inp = in + (size_t)slice * NP16;
    __half* outp = out + (size_t)slice * NP16;
    float4 b4 = make_float4(0.f, 0.f, 0.f, 0.f);
    if (bias) b4 = *(const float4*)&bias[slice * 16 + sub * 4];
    int pairs = (N + 1) >> 1;
    for (int p = sbid * 4 + w; p < pairs; p += nslots) {
        int node = p * 2 + n2;
        bool ok = node < N;
        int s = ok ? rowst[node] : 0;
        int d = ok ? degp[node] : 0;
        const int2* ep = edge + s;
        float a0 = 0.f, a1 = 0.f, a2 = 0.f, a3 = 0.f;
        for (int base = 0; base < d; base += 16) {
            int i0 = base + eg, i1 = base + eg + 8;
            long long m0 = __builtin_nontemporal_load(
                (const long long*)(ep + ((i0 < d) ? i0 : 0)));
            long long m1 = __builtin_nontemporal_load(
                (const long long*)(ep + ((i1 < d) ? i1 : 0)));
            int c0 = (int)(m0 & 0xffffffffLL);
            int c1 = (int)(m1 & 0xffffffffLL);
            float w0 = (i0 < d) ? __int_as_float((int)(m0 >> 32)) : 0.f;
            float w1 = (i1 < d) ? __int_as_float((int)(m1 >> 32)) : 0.f;
            uint2 r0 = *(const uint2*)&inp[(size_t)c0 * 16 + sub * 4];
            uint2 r1 = *(const uint2*)&inp[(size_t)c1 * 16 + sub * 4];
            fma_row(w0, r0, a0, a1, a2, a3);
            fma_row(w1, r1, a0, a1, a2, a3);
        }
        // reduce over 8 edge-groups (lane strides 4,8,16)
        a0 += __shfl_xor(a0, 4);  a1 += __shfl_xor(a1, 4);  a2 += __shfl_xor(a2, 4);  a3 += __shfl_xor(a3, 4);
        a0 += __shfl_xor(a0, 8);  a1 += __shfl_xor(a1, 8);  a2 += __shfl_xor(a2, 8);  a3 += __shfl_xor(a3, 8);
        a0 += __shfl_xor(a0, 16); a1 += __shfl_xor(a1, 16); a2 += __shfl_xor(a2, 16); a3 += __shfl_xor(a3, 16);
        a0 += b4.x; a1 += b4.y; a2 += b4.z; a3 += b4.w;
        if (relu) {
            a0 = fmaxf(a0, 0.f); a1 = fmaxf(a1, 0.f);
            a2 = fmaxf(a2, 0.f); a3 = fmaxf(a3, 0.f);
        }
        if (eg == 0 && ok)
            *(uint2*)&outp[(size_t)node * 16 + sub * 4] = pack4(a0, a1, a2, a3);
    }
}

// ---------- dense encoder: y2 = relu(p0@W1+b1)@W2 ; p0h fp16 rows, out planes ----------
__global__ __launch_bounds__(256) void k_dense(
        const __half* __restrict__ p0h, __half* __restrict__ out,
        const float* __restrict__ W1, const float* __restrict__ b1,
        const float* __restrict__ W2, int N) {
    __shared__ float zT[4][128][4];
    int t = threadIdx.x, lane = t & 63, w = t >> 6;
    int base = (blockIdx.x * 4 + w) * 4;
    if (base >= N) return;
    float p = __half2float(p0h[(size_t)base * 16 + lane]);
    float zA[4], zB[4];
    float bA = b1[lane], bB = b1[lane + 64];
    #pragma unroll
    for (int j = 0; j < 4; ++j) { zA[j] = bA; zB[j] = bB; }
    #pragma unroll
    for (int k = 0; k < 16; ++k) {
        float w1a = W1[k * 128 + lane];
        float w1b = W1[k * 128 + lane + 64];
        #pragma unroll
        for (int j = 0; j < 4; ++j) {
            float pk = __shfl(p, j * 16 + k);
            zA[j] += pk * w1a;
            zB[j] += pk * w1b;
        }
    }
    #pragma unroll
    for (int j = 0; j < 4; ++j) {
        zT[w][lane][j]      = fmaxf(zA[j], 0.f);
        zT[w][lane + 64][j] = fmaxf(zB[j], 0.f);
    }
    float acc[4] = {0.f, 0.f, 0.f, 0.f};
    #pragma unroll 4
    for (int k = 0; k < 128; ++k) {
        float wk = W2[k * 64 + lane];
        float4 zk = *(const float4*)&zT[w][k][0];
        acc[0] += zk.x * wk; acc[1] += zk.y * wk;
        acc[2] += zk.z * wk; acc[3] += zk.w * wk;
    }
    size_t NP16 = (size_t)N * 16;
    size_t po = (size_t)(lane >> 4) * NP16 + (lane & 15);
    #pragma unroll
    for (int j = 0; j < 4; ++j)
        if (base + j < N)
            out[po + (size_t)(base + j) * 16] = __float2half(acc[j]);
}

// ---------- streaming 64x64 GEMM over planes: out = in@W (+gbias) ----------
__global__ __launch_bounds__(256) void k_gemm64(
        const __half* __restrict__ in, __half* __restrict__ out,
        const float* __restrict__ W, const float* __restrict__ gbias, int N) {
    __shared__ float Wlds[64 * 64];
    __shared__ float zs[8][64];
    int t = threadIdx.x, lane = t & 63, w = t >> 6;
    for (int i = t; i < 64 * 64 / 4; i += 256)
        ((float4*)Wlds)[i] = ((const float4*)W)[i];
    __syncthreads();
    float gb = gbias ? gbias[lane] : 0.f;
    size_t NP16 = (size_t)N * 16;
    int groups = (N + 7) >> 3;
    int nl = t >> 5, u = t & 31;         // staging map: node-local, uint idx
    int ss = u >> 3, dp = u & 7;
    for (int gi = blockIdx.x; gi < groups; gi += gridDim.x) {
        int base = gi * 8;
        {
            int node = base + nl;
            unsigned v = 0;
            if (node < N)
                v = *(const unsigned*)&in[(size_t)ss * NP16 + (size_t)node * 16 + dp * 2];
            float2 f = __half22float2(*(__half2*)&v);
            zs[nl][ss * 16 + dp * 2]     = f.x;
            zs[nl][ss * 16 + dp * 2 + 1] = f.y;
        }
        __syncthreads();
        int n0 = base + w * 2, n1 = n0 + 1;
        float acc0 = gb, acc1 = gb;
        #pragma unroll 8
        for (int k = 0; k < 64; ++k) {
            float wk = Wlds[k * 64 + lane];
            acc0 += zs[w * 2][k] * wk;
            acc1 += zs[w * 2 + 1][k] * wk;
        }
        size_t po = (size_t)(lane >> 4) * NP16 + (lane & 15);
        if (n0 < N) out[po + (size_t)n0 * 16] = __float2half(acc0);
        if (n1 < N) out[po + (size_t)n1 * 16] = __float2half(acc1);
        __syncthreads();
    }
}

// ---------- pooling + head ----------
__global__ void k_pool_init(unsigned* __restrict__ gmax) {
    gmax[blockIdx.x * 64 + threadIdx.x] = fmap(-INFINITY);
}

__global__ void k_pool(const __half* __restrict__ z, const int* __restrict__ batch,
                       unsigned* __restrict__ gmax, int N) {
    int f = threadIdx.x & 63, w = threadIdx.x >> 6;
    int base = (blockIdx.x * 4 + w) * 32;
    if (base >= N) return;
    int end = base + 32; if (end > N) end = N;
    size_t NP16 = (size_t)N * 16;
    const __half* zf = z + (size_t)(f >> 4) * NP16 + (f & 15);
    int b0 = batch[base], b1 = batch[end - 1];
    if (b0 == b1) {
        float lmax = -INFINITY;
        for (int n = base; n < end; ++n)
            lmax = fmaxf(lmax, __half2float(zf[(size_t)n * 16]));
        atomicMax(&gmax[b0 * 64 + f], fmap(lmax));
    } else {
        int curb = b0; float lmax = -INFINITY;
        for (int n = base; n < end; ++n) {
            int b = batch[n];
            if (b != curb) {
                atomicMax(&gmax[curb * 64 + f], fmap(lmax));
                curb = b; lmax = -INFINITY;
            }
            lmax = fmaxf(lmax, __half2float(zf[(size_t)n * 16]));
        }
        atomicMax(&gmax[curb * 64 + f], fmap(lmax));
    }
}

__global__ void k_head(const unsigned* __restrict__ gmax,
                       const float* __restrict__ Wf1, const float* __restrict__ bf1,
                       const float* __restrict__ Wf2, const float* __restrict__ bf2,
                       const float* __restrict__ Wc, const float* __restrict__ bc,
                       const float* __restrict__ Wcb, const float* __restrict__ bcb,
                       float* __restrict__ out) {
    __shared__ float g[8][64], h1[8][32], h2[8][16];
    int t = threadIdx.x;
    for (int i = t; i < 512; i += 64) g[i >> 6][i & 63] = funmap(gmax[i]);
    __syncthreads();
    for (int i = t; i < 256; i += 64) {
        int r = i >> 5, c = i & 31;
        float a = bf1[c];
        for (int k = 0; k < 64; ++k) a += g[r][k] * Wf1[k * 32 + c];
        h1[r][c] = fmaxf(a, 0.f);
    }
    __syncthreads();
    for (int i = t; i < 128; i += 64) {
        int r = i >> 4, c = i & 15;
        float a = bf2[c];
        for (int k = 0; k < 32; ++k) a += h1[r][k] * Wf2[k * 16 + c];
        h2[r][c] = fmaxf(a, 0.f);
    }
    __syncthreads();
    if (t < 16) {
        int r = t & 7;
        bool comb = t >= 8;
        const float* W = comb ? Wcb : Wc;
        float a = comb ? bcb[0] : bc[0];
        for (int k = 0; k < 16; ++k) a += h2[r][k] * W[k];
        out[(comb ? 8 : 0) + r] = a;
    }
}

// ---------- launch ----------
extern "C" void kernel_launch(void* const* d_in, const int* in_sizes, int n_in,
                              void* d_out, int out_size, void* d_ws, size_t ws_size,
                              hipStream_t stream) {
    const float* x    = (const float*)d_in[0];
    const int*   ei   = (const int*)d_in[1];
    const int*   batch= (const int*)d_in[2];
    const float* W1   = (const float*)d_in[3];
    const float* b1   = (const float*)d_in[4];
    const float* W2   = (const float*)d_in[5];
    const float* b2   = (const float*)d_in[6];
    const float* Wg1  = (const float*)d_in[7];
    const float* bg1  = (const float*)d_in[8];
    const float* Wg2  = (const float*)d_in[9];
    const float* bg2  = (const float*)d_in[10];
    const float* Wg3  = (const float*)d_in[11];
    const float* bg3  = (const float*)d_in[12];
    const float* Wsg  = (const float*)d_in[13];
    const float* bsg  = (const float*)d_in[14];
    const float* Wf1  = (const float*)d_in[15];
    const float* bf1  = (const float*)d_in[16];
    const float* Wf2  = (const float*)d_in[17];
    const float* bf2  = (const float*)d_in[18];
    const float* Wc   = (const float*)d_in[19];
    const float* bc   = (const float*)d_in[20];
    const float* Wcb  = (const float*)d_in[21];
    const float* bcb  = (const float*)d_in[22];

    const int N = in_sizes[0] / 16;
    const int E = in_sizes[1] / 2;
    const int* esrc = ei;
    const int* edst = ei + E;

    char* ws = (char*)d_ws;
    auto alloc = [&](size_t bytes) -> char* {
        char* p = ws;
        ws += (bytes + 255) & ~(size_t)255;
        return p;
    };
    int*      deg   = (int*)alloc((size_t)N * 4);
    int*      degp  = (int*)alloc((size_t)N * 4);
    int*      cnt   = (int*)alloc((size_t)N * 4);
    int*      rowst = (int*)alloc((size_t)(N + 1) * 4);
    int*      bsum  = (int*)alloc(4096);
    float*    dis   = (float*)alloc((size_t)N * 4);
    int2*     edge  = (int2*)alloc((size_t)(E + N + 16) * 8);
    __half*   xh    = (__half*)alloc((size_t)N * 16 * 2);
    __half*   p0h   = (__half*)alloc((size_t)N * 16 * 2);
    __half*   bufA  = (__half*)alloc((size_t)N * 64 * 2);
    __half*   bufB  = (__half*)alloc((size_t)N * 64 * 2);
    unsigned* gmax  = (unsigned*)alloc((size_t)G_GRAPHS * 64 * 4);

    hipMemsetAsync(deg, 0, (size_t)N * 4, stream);
    hipMemsetAsync(cnt, 0, (size_t)N * 4, stream);

    const int EB = (E + 255) / 256;
    const int NB = (N + 255) / 256;
    const int PB = 2048;   // prop blocks: 512 per feature-slice
    const int GB = 1024;   // gemm blocks

    k_count<<<EB, 256, 0, stream>>>(edst, deg, E);
    k_dis<<<NB, 256, 0, stream>>>(deg, dis, degp, N);
    k_scanA<<<NB, 256, 0, stream>>>(deg, rowst, bsum, N);
    k_scanB<<<1, 512, 0, stream>>>(bsum, NB);
    k_scanC<<<NB, 256, 0, stream>>>(rowst, bsum, N);
    k_self<<<NB, 256, 0, stream>>>(rowst, deg, edge, N);
    k_fill<<<EB, 256, 0, stream>>>(esrc, edst, dis, rowst, cnt, edge, E);
    k_x2h<<<(N * 4 + 255) / 256, 256, 0, stream>>>(x, xh, N * 4);

    // encoder: p0 = prop(x) (dim16, unsliced: xh is one plane, L2-replicated)
    k_prop<<<PB, 256, 0, stream>>>(xh, p0h, rowst, degp, edge, nullptr, 0, N, 0, 0);
    // y2 = relu(p0@W1+b1)@W2 -> planes A
    k_dense<<<(N + 15) / 16, 256, 0, stream>>>(p0h, bufA, W1, b1, W2, N);
    // z2 = prop(y2)+b2 ; A2 = z2@Wg1
    k_prop<<<PB, 256, 0, stream>>>(bufA, bufB, rowst, degp, edge, b2, 0, N, 3, 2);
    k_gemm64<<<GB, 256, 0, stream>>>(bufB, bufA, Wg1, nullptr, N);
    // z3 = relu(prop(.)+bg1) ; . = z3@Wg2
    k_prop<<<PB, 256, 0, stream>>>(bufA, bufB, rowst, degp, edge, bg1, 1, N, 3, 2);
    k_gemm64<<<GB, 256, 0, stream>>>(bufB, bufA, Wg2, nullptr, N);
    // z4 = relu(prop(.)+bg2) ; . = z4@Wg3
    k_prop<<<PB, 256, 0, stream>>>(bufA, bufB, rowst, degp, edge, bg2, 1, N, 3, 2);
    k_gemm64<<<GB, 256, 0, stream>>>(bufB, bufA, Wg3, nullptr, N);
    // z5 = relu(prop(.)+bg3)
    k_prop<<<PB, 256, 0, stream>>>(bufA, bufB, rowst, degp, edge, bg3, 1, N, 3, 2);
    // SGConv: 4 plain props, then @Wsg+bsg
    k_prop<<<PB, 256, 0, stream>>>(bufB, bufA, rowst, degp, edge, nullptr, 0, N, 3, 2);
    k_prop<<<PB, 256, 0, stream>>>(bufA, bufB, rowst, degp, edge, nullptr, 0, N, 3, 2);
    k_prop<<<PB, 256, 0, stream>>>(bufB, bufA, rowst, degp, edge, nullptr, 0, N, 3, 2);
    k_prop<<<PB, 256, 0, stream>>>(bufA, bufB, rowst, degp, edge, nullptr, 0, N, 3, 2);
    k_gemm64<<<GB, 256, 0, stream>>>(bufB, bufA, Wsg, bsg, N);

    // pool + head
    k_pool_init<<<G_GRAPHS, 64, 0, stream>>>(gmax);
    k_pool<<<(N + 127) / 128, 256, 0, stream>>>(bufA, batch, gmax, N);
    k_head<<<1, 64, 0, stream>>>(gmax, Wf1, bf1, Wf2, bf2, Wc, bc, Wcb, bcb, (float*)d_out);
}

// Round 10
// 672.077 us; speedup vs baseline: 1.4046x; 1.4046x over previous
//
#include <hip/hip_runtime.h>
#include <hip/hip_fp16.h>
#include <math.h>

#define G_GRAPHS 8

// ---------- helpers ----------
__device__ __forceinline__ unsigned fmap(float f) {
    unsigned b = __float_as_uint(f);
    return (b & 0x80000000u) ? ~b : (b | 0x80000000u);
}
__device__ __forceinline__ float funmap(unsigned u) {
    unsigned b = (u & 0x80000000u) ? (u & 0x7fffffffu) : ~u;
    return __uint_as_float(b);
}
__device__ __forceinline__ void fma_row(float wv, uint2 r,
                                        float& ax, float& ay, float& az, float& aw) {
    float2 f01 = __half22float2(*(__half2*)&r.x);
    float2 f23 = __half22float2(*(__half2*)&r.y);
    ax += wv * f01.x; ay += wv * f01.y; az += wv * f23.x; aw += wv * f23.y;
}
__device__ __forceinline__ uint2 pack4(float ax, float ay, float az, float aw) {
    __half2 p01 = __float22half2_rn(make_float2(ax, ay));
    __half2 p23 = __float22half2_rn(make_float2(az, aw));
    uint2 r;
    r.x = *(unsigned*)&p01;
    r.y = *(unsigned*)&p23;
    return r;
}

// ---------- CSR build (self-loop folded in as slot 0 of each row) ----------
__global__ void k_count(const int* __restrict__ dst, int* __restrict__ deg, int E) {
    int e = blockIdx.x * 256 + threadIdx.x;
    if (e < E) atomicAdd(&deg[dst[e]], 1);
}

__global__ void k_dis(const int* __restrict__ deg, float* __restrict__ dis,
                      int* __restrict__ degp, int N) {
    int i = blockIdx.x * 256 + threadIdx.x;
    if (i < N) {
        int d = deg[i];
        dis[i] = rsqrtf((float)(d + 1));
        degp[i] = d + 1;                 // incl. self loop
    }
}

__global__ void k_scanA(const int* __restrict__ deg, int* __restrict__ rowst,
                        int* __restrict__ bsum, int N) {
    __shared__ int s[256];
    int i = blockIdx.x * 256 + threadIdx.x;
    int v = (i < N) ? deg[i] + 1 : 0;    // +1 self loop
    s[threadIdx.x] = v;
    __syncthreads();
    for (int off = 1; off < 256; off <<= 1) {
        int t = (threadIdx.x >= off) ? s[threadIdx.x - off] : 0;
        __syncthreads();
        s[threadIdx.x] += t;
        __syncthreads();
    }
    if (i < N) rowst[i] = s[threadIdx.x] - v;
    if (threadIdx.x == 255) bsum[blockIdx.x] = s[255];
}

__global__ void k_scanB(int* __restrict__ bsum, int NB) {
    __shared__ int s[512];
    int t = threadIdx.x;
    int v = (t < NB) ? bsum[t] : 0;
    s[t] = v;
    __syncthreads();
    for (int off = 1; off < 512; off <<= 1) {
        int x = (t >= off) ? s[t - off] : 0;
        __syncthreads();
        s[t] += x;
        __syncthreads();
    }
    if (t < NB) bsum[t] = s[t] - v;
}

__global__ void k_scanC(int* __restrict__ rowst, const int* __restrict__ bsum, int N) {
    int i = blockIdx.x * 256 + threadIdx.x;
    if (i < N) rowst[i] += bsum[blockIdx.x];
}

__global__ void k_self(const int* __restrict__ rowst, const int* __restrict__ deg,
                       int2* __restrict__ edge, int N) {
    int i = blockIdx.x * 256 + threadIdx.x;
    if (i < N) {
        float sw = 1.0f / (float)(deg[i] + 1);   // dis^2
        edge[rowst[i]] = make_int2(i, __float_as_int(sw));
    }
}

__global__ void k_fill(const int* __restrict__ src, const int* __restrict__ dst,
                       const float* __restrict__ dis, const int* __restrict__ rowst,
                       int* __restrict__ cnt, int2* __restrict__ edge, int E) {
    int e = blockIdx.x * 256 + threadIdx.x;
    if (e >= E) return;
    int d = dst[e], s = src[e];
    int p = rowst[d] + 1 + atomicAdd(&cnt[d], 1);   // slot 0 = self
    edge[p] = make_int2(s, __float_as_int(dis[s] * dis[d]));
}

// ---------- x -> fp16 ----------
__global__ void k_x2h(const float* __restrict__ x, __half* __restrict__ xh, int n4) {
    int i = blockIdx.x * 256 + threadIdx.x;
    if (i >= n4) return;
    float4 v = ((const float4*)x)[i];
    ((uint2*)xh)[i] = pack4(v.x, v.y, v.z, v.w);
}

// ---------- prop16: p0 = prop(x) dim16 (fp16 rows, fp32 out); 4 lanes/node ----------
__global__ __launch_bounds__(256) void k_prop16(
        const __half* __restrict__ xh, float* __restrict__ out,
        const int* __restrict__ rowst, const int* __restrict__ degp,
        const int2* __restrict__ edge, int N) {
    int t = threadIdx.x, lane = t & 63, w = t >> 6;
    int grp = lane >> 2, sub = lane & 3;
    int node = blockIdx.x * 64 + w * 16 + grp;
    if (node >= N) return;
    const uint2* xr = (const uint2*)xh;        // row = 4 uint2 (32 B)
    float ax = 0.f, ay = 0.f, az = 0.f, aw = 0.f;
    int s = rowst[node], d = degp[node];
    const int2* ep = edge + s;
    for (int i = 0; i < d; i += 4) {
        int j0 = i, j1 = i + 1, j2 = i + 2, j3 = i + 3;
        long long m0 = __builtin_nontemporal_load((const long long*)(ep + j0));
        long long m1 = __builtin_nontemporal_load((const long long*)(ep + ((j1 < d) ? j1 : 0)));
        long long m2 = __builtin_nontemporal_load((const long long*)(ep + ((j2 < d) ? j2 : 0)));
        long long m3 = __builtin_nontemporal_load((const long long*)(ep + ((j3 < d) ? j3 : 0)));
        uint2 r0 = xr[(size_t)(int)(m0 & 0xffffffffLL) * 4 + sub];
        uint2 r1 = xr[(size_t)(int)(m1 & 0xffffffffLL) * 4 + sub];
        uint2 r2 = xr[(size_t)(int)(m2 & 0xffffffffLL) * 4 + sub];
        uint2 r3 = xr[(size_t)(int)(m3 & 0xffffffffLL) * 4 + sub];
        float w0 = __int_as_float((int)(m0 >> 32));
        float w1 = (j1 < d) ? __int_as_float((int)(m1 >> 32)) : 0.f;
        float w2 = (j2 < d) ? __int_as_float((int)(m2 >> 32)) : 0.f;
        float w3 = (j3 < d) ? __int_as_float((int)(m3 >> 32)) : 0.f;
        fma_row(w0, r0, ax, ay, az, aw);
        fma_row(w1, r1, ax, ay, az, aw);
        fma_row(w2, r2, ax, ay, az, aw);
        fma_row(w3, r3, ax, ay, az, aw);
    }
    ((float4*)out)[node * 4 + sub] = make_float4(ax, ay, az, aw);
}

// ---------- dense: y2 = relu(p0@W1+b1)@W2 (fp32 in, fp16 out); wave per 4-node quad ----------
__global__ __launch_bounds__(256) void k_dense(
        const float* __restrict__ p0, __half* __restrict__ out,
        const float* __restrict__ W1, const float* __restrict__ b1,
        const float* __restrict__ W2, int N) {
    __shared__ float zT[4][128][4];
    int t = threadIdx.x, lane = t & 63, w = t >> 6;
    int base = (blockIdx.x * 4 + w) * 4;
    if (base >= N) return;
    float p = p0[(size_t)base * 16 + lane];
    float zA[4], zB[4];
    float bA = b1[lane], bB = b1[lane + 64];
    #pragma unroll
    for (int j = 0; j < 4; ++j) { zA[j] = bA; zB[j] = bB; }
    #pragma unroll
    for (int k = 0; k < 16; ++k) {
        float w1a = W1[k * 128 + lane];
        float w1b = W1[k * 128 + lane + 64];
        #pragma unroll
        for (int j = 0; j < 4; ++j) {
            float pk = __shfl(p, j * 16 + k);
            zA[j] += pk * w1a;
            zB[j] += pk * w1b;
        }
    }
    #pragma unroll
    for (int j = 0; j < 4; ++j) {
        zT[w][lane][j]      = fmaxf(zA[j], 0.f);
        zT[w][lane + 64][j] = fmaxf(zB[j], 0.f);
    }
    float acc[4] = {0.f, 0.f, 0.f, 0.f};
    #pragma unroll 4
    for (int k = 0; k < 128; ++k) {
        float wk = W2[k * 64 + lane];
        float4 zk = *(const float4*)&zT[w][k][0];
        acc[0] += zk.x * wk; acc[1] += zk.y * wk;
        acc[2] += zk.z * wk; acc[3] += zk.w * wk;
    }
    #pragma unroll
    for (int j = 0; j < 4; ++j)
        if (base + j < N) out[(size_t)(base + j) * 64 + lane] = __float2half(acc[j]);
}

// ---------- prop64 (persistent, 2 nodes/wave, fp16 rows) ----------
// z = prop(in)+bias [relu]; out = HASW ? z@W(+gbias) : z
// dynamic LDS: HASW ? 10240 B (W as half2-pairs + zbuf) : 0
template<bool HASW>
__global__ __launch_bounds__(256) void k_prop64(
        const __half* __restrict__ in, __half* __restrict__ out,
        const int* __restrict__ rowst, const int* __restrict__ degp,
        const int2* __restrict__ edge,
        const float* __restrict__ bias, int relu,
        const float* __restrict__ W, const float* __restrict__ gbias, int N) {
    extern __shared__ char smem[];
    unsigned* Whl = (unsigned*)smem;              // [32][64] packed half2 (W[2k],W[2k+1])
    float* zb = (float*)(smem + 8192);            // [4][2][64]
    int t = threadIdx.x, lane = t & 63, w = t >> 6;
    int q = lane & 15, g = lane >> 4;             // 16 lanes x 4 edge-groups
    const uint2* inr = (const uint2*)in;          // row = 16 uint2 (128 B)
    if (HASW) {
        for (int i = t; i < 2048; i += 256) {
            int kk = i >> 6, l = i & 63;
            __half2 h = __floats2half2_rn(make_float2(W[(2 * kk) * 64 + l],
                                                      W[(2 * kk + 1) * 64 + l]).x,
                                          make_float2(W[(2 * kk) * 64 + l],
                                                      W[(2 * kk + 1) * 64 + l]).y);
            // (avoid compiler confusion: explicit)
            __half2 hh; hh.x = __float2half(W[(2 * kk) * 64 + l]);
            hh.y = __float2half(W[(2 * kk + 1) * 64 + l]);
            Whl[i] = *(unsigned*)&hh;
        }
        __syncthreads();
    }
    float4 b4 = make_float4(0.f, 0.f, 0.f, 0.f);
    if (bias) b4 = ((const float4*)bias)[q];
    float gb = (HASW && gbias) ? gbias[lane] : 0.f;
    int wid = blockIdx.x * 4 + w;
    const int stride = gridDim.x * 4 * 2;
    for (int n0 = wid * 2; n0 < N; n0 += stride) {
        int n1 = n0 + 1;
        bool h1 = n1 < N;
        int s0 = rowst[n0], d0 = degp[n0];
        int s1 = h1 ? rowst[n1] : s0, d1 = h1 ? degp[n1] : 0;
        const int2* e0 = edge + s0;
        const int2* e1 = edge + s1;
        float a0x = 0.f, a0y = 0.f, a0z = 0.f, a0w = 0.f;
        float a1x = 0.f, a1y = 0.f, a1z = 0.f, a1w = 0.f;
        int m = d0 > d1 ? d0 : d1;
        for (int base = 0; base < m; base += 16) {
            int i0 = base + g, i1 = i0 + 4, i2 = i0 + 8, i3 = i0 + 12;
            long long ma0 = __builtin_nontemporal_load((const long long*)(e0 + ((i0 < d0) ? i0 : 0)));
            long long ma1 = __builtin_nontemporal_load((const long long*)(e0 + ((i1 < d0) ? i1 : 0)));
            long long ma2 = __builtin_nontemporal_load((const long long*)(e0 + ((i2 < d0) ? i2 : 0)));
            long long ma3 = __builtin_nontemporal_load((const long long*)(e0 + ((i3 < d0) ? i3 : 0)));
            long long mb0 = __builtin_nontemporal_load((const long long*)(e1 + ((i0 < d1) ? i0 : 0)));
            long long mb1 = __builtin_nontemporal_load((const long long*)(e1 + ((i1 < d1) ? i1 : 0)));
            long long mb2 = __builtin_nontemporal_load((const long long*)(e1 + ((i2 < d1) ? i2 : 0)));
            long long mb3 = __builtin_nontemporal_load((const long long*)(e1 + ((i3 < d1) ? i3 : 0)));
            uint2 ra0 = inr[(size_t)(int)(ma0 & 0xffffffffLL) * 16 + q];
            uint2 ra1 = inr[(size_t)(int)(ma1 & 0xffffffffLL) * 16 + q];
            uint2 ra2 = inr[(size_t)(int)(ma2 & 0xffffffffLL) * 16 + q];
            uint2 ra3 = inr[(size_t)(int)(ma3 & 0xffffffffLL) * 16 + q];
            uint2 rb0 = inr[(size_t)(int)(mb0 & 0xffffffffLL) * 16 + q];
            uint2 rb1 = inr[(size_t)(int)(mb1 & 0xffffffffLL) * 16 + q];
            uint2 rb2 = inr[(size_t)(int)(mb2 & 0xffffffffLL) * 16 + q];
            uint2 rb3 = inr[(size_t)(int)(mb3 & 0xffffffffLL) * 16 + q];
            float wa0 = (i0 < d0) ? __int_as_float((int)(ma0 >> 32)) : 0.f;
            float wa1 = (i1 < d0) ? __int_as_float((int)(ma1 >> 32)) : 0.f;
            float wa2 = (i2 < d0) ? __int_as_float((int)(ma2 >> 32)) : 0.f;
            float wa3 = (i3 < d0) ? __int_as_float((int)(ma3 >> 32)) : 0.f;
            float wb0 = (i0 < d1) ? __int_as_float((int)(mb0 >> 32)) : 0.f;
            float wb1 = (i1 < d1) ? __int_as_float((int)(mb1 >> 32)) : 0.f;
            float wb2 = (i2 < d1) ? __int_as_float((int)(mb2 >> 32)) : 0.f;
            float wb3 = (i3 < d1) ? __int_as_float((int)(mb3 >> 32)) : 0.f;
            fma_row(wa0, ra0, a0x, a0y, a0z, a0w);
            fma_row(wa1, ra1, a0x, a0y, a0z, a0w);
            fma_row(wa2, ra2, a0x, a0y, a0z, a0w);
            fma_row(wa3, ra3, a0x, a0y, a0z, a0w);
            fma_row(wb0, rb0, a1x, a1y, a1z, a1w);
            fma_row(wb1, rb1, a1x, a1y, a1z, a1w);
            fma_row(wb2, rb2, a1x, a1y, a1z, a1w);
            fma_row(wb3, rb3, a1x, a1y, a1z, a1w);
        }
        // reduce the 4 edge-groups: xor 16, 32
        a0x += __shfl_xor(a0x,16); a0y += __shfl_xor(a0y,16); a0z += __shfl_xor(a0z,16); a0w += __shfl_xor(a0w,16);
        a0x += __shfl_xor(a0x,32); a0y += __shfl_xor(a0y,32); a0z += __shfl_xor(a0z,32); a0w += __shfl_xor(a0w,32);
        a1x += __shfl_xor(a1x,16); a1y += __shfl_xor(a1y,16); a1z += __shfl_xor(a1z,16); a1w += __shfl_xor(a1w,16);
        a1x += __shfl_xor(a1x,32); a1y += __shfl_xor(a1y,32); a1z += __shfl_xor(a1z,32); a1w += __shfl_xor(a1w,32);
        a0x += b4.x; a0y += b4.y; a0z += b4.z; a0w += b4.w;
        a1x += b4.x; a1y += b4.y; a1z += b4.z; a1w += b4.w;
        if (relu) {
            a0x = fmaxf(a0x,0.f); a0y = fmaxf(a0y,0.f); a0z = fmaxf(a0z,0.f); a0w = fmaxf(a0w,0.f);
            a1x = fmaxf(a1x,0.f); a1y = fmaxf(a1y,0.f); a1z = fmaxf(a1z,0.f); a1w = fmaxf(a1w,0.f);
        }
        if (!HASW) {
            if (g == 0) {
                ((uint2*)out)[(size_t)n0 * 16 + q] = pack4(a0x, a0y, a0z, a0w);
                if (h1) ((uint2*)out)[(size_t)n1 * 16 + q] = pack4(a1x, a1y, a1z, a1w);
            }
        } else {
            if (g == 0) {
                ((float4*)&zb[(w * 2 + 0) * 64])[q] = make_float4(a0x, a0y, a0z, a0w);
                ((float4*)&zb[(w * 2 + 1) * 64])[q] = make_float4(a1x, a1y, a1z, a1w);
            }
            // wave-local LDS RAW: in-order per wave
            float acc0 = gb, acc1 = gb;
            #pragma unroll 8
            for (int kk = 0; kk < 32; ++kk) {
                unsigned u = Whl[kk * 64 + lane];
                float2 wp = __half22float2(*(__half2*)&u);
                float2 z0 = *(float2*)&zb[(w * 2 + 0) * 64 + 2 * kk];
                float2 z1 = *(float2*)&zb[(w * 2 + 1) * 64 + 2 * kk];
                acc0 += z0.x * wp.x + z0.y * wp.y;
                acc1 += z1.x * wp.x + z1.y * wp.y;
            }
            out[(size_t)n0 * 64 + lane] = __float2half(acc0);
            if (h1) out[(size_t)n1 * 64 + lane] = __float2half(acc1);
        }
    }
}

// ---------- pooling + head ----------
__global__ void k_pool_init(unsigned* __restrict__ gmax) {
    gmax[blockIdx.x * 64 + threadIdx.x] = fmap(-INFINITY);
}

__global__ void k_pool(const __half* __restrict__ z, const int* __restrict__ batch,
                       unsigned* __restrict__ gmax, int N) {
    int f = threadIdx.x & 63, w = threadIdx.x >> 6;
    int base = (blockIdx.x * 4 + w) * 32;
    if (base >= N) return;
    int end = base + 32; if (end > N) end = N;
    int b0 = batch[base], b1 = batch[end - 1];
    if (b0 == b1) {
        float lmax = -INFINITY;
        for (int n = base; n < end; ++n)
            lmax = fmaxf(lmax, __half2float(z[(size_t)n * 64 + f]));
        atomicMax(&gmax[b0 * 64 + f], fmap(lmax));
    } else {
        int curb = b0; float lmax = -INFINITY;
        for (int n = base; n < end; ++n) {
            int b = batch[n];
            if (b != curb) {
                atomicMax(&gmax[curb * 64 + f], fmap(lmax));
                curb = b; lmax = -INFINITY;
            }
            lmax = fmaxf(lmax, __half2float(z[(size_t)n * 64 + f]));
        }
        atomicMax(&gmax[curb * 64 + f], fmap(lmax));
    }
}

__global__ void k_head(const unsigned* __restrict__ gmax,
                       const float* __restrict__ Wf1, const float* __restrict__ bf1,
                       const float* __restrict__ Wf2, const float* __restrict__ bf2,
                       const float* __restrict__ Wc, const float* __restrict__ bc,
                       const float* __restrict__ Wcb, const float* __restrict__ bcb,
                       float* __restrict__ out) {
    __shared__ float g[8][64], h1[8][32], h2[8][16];
    int t = threadIdx.x;
    for (int i = t; i < 512; i += 64) g[i >> 6][i & 63] = funmap(gmax[i]);
    __syncthreads();
    for (int i = t; i < 256; i += 64) {
        int r = i >> 5, c = i & 31;
        float a = bf1[c];
        for (int k = 0; k < 64; ++k) a += g[r][k] * Wf1[k * 32 + c];
        h1[r][c] = fmaxf(a, 0.f);
    }
    __syncthreads();
    for (int i = t; i < 128; i += 64) {
        int r = i >> 4, c = i & 15;
        float a = bf2[c];
        for (int k = 0; k < 32; ++k) a += h1[r][k] * Wf2[k * 16 + c];
        h2[r][c] = fmaxf(a, 0.f);
    }
    __syncthreads();
    if (t < 16) {
        int r = t & 7;
        bool comb = t >= 8;
        const float* W = comb ? Wcb : Wc;
        float a = comb ? bcb[0] : bc[0];
        for (int k = 0; k < 16; ++k) a += h2[r][k] * W[k];
        out[(comb ? 8 : 0) + r] = a;
    }
}

// ---------- launch ----------
extern "C" void kernel_launch(void* const* d_in, const int* in_sizes, int n_in,
                              void* d_out, int out_size, void* d_ws, size_t ws_size,
                              hipStream_t stream) {
    const float* x    = (const float*)d_in[0];
    const int*   ei   = (const int*)d_in[1];
    const int*   batch= (const int*)d_in[2];
    const float* W1   = (const float*)d_in[3];
    const float* b1   = (const float*)d_in[4];
    const float* W2   = (const float*)d_in[5];
    const float* b2   = (const float*)d_in[6];
    const float* Wg1  = (const float*)d_in[7];
    const float* bg1  = (const float*)d_in[8];
    const float* Wg2  = (const float*)d_in[9];
    const float* bg2  = (const float*)d_in[10];
    const float* Wg3  = (const float*)d_in[11];
    const float* bg3  = (const float*)d_in[12];
    const float* Wsg  = (const float*)d_in[13];
    const float* bsg  = (const float*)d_in[14];
    const float* Wf1  = (const float*)d_in[15];
    const float* bf1  = (const float*)d_in[16];
    const float* Wf2  = (const float*)d_in[17];
    const float* bf2  = (const float*)d_in[18];
    const float* Wc   = (const float*)d_in[19];
    const float* bc   = (const float*)d_in[20];
    const float* Wcb  = (const float*)d_in[21];
    const float* bcb  = (const float*)d_in[22];

    const int N = in_sizes[0] / 16;
    const int E = in_sizes[1] / 2;
    const int* esrc = ei;
    const int* edst = ei + E;

    char* ws = (char*)d_ws;
    auto alloc = [&](size_t bytes) -> char* {
        char* p = ws;
        ws += (bytes + 255) & ~(size_t)255;
        return p;
    };
    int*      deg   = (int*)alloc((size_t)N * 4);
    int*      degp  = (int*)alloc((size_t)N * 4);
    int*      cnt   = (int*)alloc((size_t)N * 4);
    int*      rowst = (int*)alloc((size_t)(N + 1) * 4);
    int*      bsum  = (int*)alloc(4096);
    float*    dis   = (float*)alloc((size_t)N * 4);
    int2*     edge  = (int2*)alloc((size_t)(E + N + 16) * 8);
    __half*   xh    = (__half*)alloc((size_t)N * 16 * 2);
    float*    p0    = (float*)alloc((size_t)N * 16 * 4);
    __half*   bufA  = (__half*)alloc((size_t)N * 64 * 2);
    __half*   bufB  = (__half*)alloc((size_t)N * 64 * 2);
    unsigned* gmax  = (unsigned*)alloc((size_t)G_GRAPHS * 64 * 4);

    hipMemsetAsync(deg, 0, (size_t)N * 4, stream);
    hipMemsetAsync(cnt, 0, (size_t)N * 4, stream);

    const int EB = (E + 255) / 256;
    const int NB = (N + 255) / 256;
    const int PB = 2048;
    const size_t SW = 10240;   // dynamic LDS for HASW props

    k_count<<<EB, 256, 0, stream>>>(edst, deg, E);
    k_dis<<<NB, 256, 0, stream>>>(deg, dis, degp, N);
    k_scanA<<<NB, 256, 0, stream>>>(deg, rowst, bsum, N);
    k_scanB<<<1, 512, 0, stream>>>(bsum, NB);
    k_scanC<<<NB, 256, 0, stream>>>(rowst, bsum, N);
    k_self<<<NB, 256, 0, stream>>>(rowst, deg, edge, N);
    k_fill<<<EB, 256, 0, stream>>>(esrc, edst, dis, rowst, cnt, edge, E);
    k_x2h<<<(N * 4 + 255) / 256, 256, 0, stream>>>(x, xh, N * 4);

    // encoder: p0 = prop(x); y2 = relu(p0@W1+b1)@W2
    k_prop16<<<(N + 63) / 64, 256, 0, stream>>>(xh, p0, rowst, degp, edge, N);
    k_dense<<<(N + 15) / 16, 256, 0, stream>>>(p0, bufA, W1, b1, W2, N);
    // z2 = prop(y2)+b2 ; out = z2@Wg1
    k_prop64<true><<<PB, 256, SW, stream>>>(bufA, bufB, rowst, degp, edge, b2, 0, Wg1, nullptr, N);
    // z3 = relu(prop(.)+bg1) ; out = z3@Wg2
    k_prop64<true><<<PB, 256, SW, stream>>>(bufB, bufA, rowst, degp, edge, bg1, 1, Wg2, nullptr, N);
    // z4 = relu(prop(.)+bg2) ; out = z4@Wg3
    k_prop64<true><<<PB, 256, SW, stream>>>(bufA, bufB, rowst, degp, edge, bg2, 1, Wg3, nullptr, N);
    // z5 = relu(prop(.)+bg3)
    k_prop64<false><<<PB, 256, 0, stream>>>(bufB, bufA, rowst, degp, edge, bg3, 1, nullptr, nullptr, N);
    // SGConv: 3 plain props, then prop + @Wsg + bsg
    k_prop64<false><<<PB, 256, 0, stream>>>(bufA, bufB, rowst, degp, edge, nullptr, 0, nullptr, nullptr, N);
    k_prop64<false><<<PB, 256, 0, stream>>>(bufB, bufA, rowst, degp, edge, nullptr, 0, nullptr, nullptr, N);
    k_prop64<false><<<PB, 256, 0, stream>>>(bufA, bufB, rowst, degp, edge, nullptr, 0, nullptr, nullptr, N);
    k_prop64<true><<<PB, 256, SW, stream>>>(bufB, bufA, rowst, degp, edge, nullptr, 0, Wsg, bsg, N);

    // pool + head
    k_pool_init<<<G_GRAPHS, 64, 0, stream>>>(gmax);
    k_pool<<<(N + 127) / 128, 256, 0, stream>>>(bufA, batch, gmax, N);
    k_head<<<1, 64, 0, stream>>>(gmax, Wf1, bf1, Wf2, bf2, Wc, bc, Wcb, bcb, (float*)d_out);
}

// Round 12
// 662.747 us; speedup vs baseline: 1.4244x; 1.0141x over previous
//
#include <hip/hip_runtime.h>
#include <hip/hip_fp16.h>
#include <math.h>

#define G_GRAPHS 8

// ---------- helpers ----------
__device__ __forceinline__ unsigned fmap(float f) {
    unsigned b = __float_as_uint(f);
    return (b & 0x80000000u) ? ~b : (b | 0x80000000u);
}
__device__ __forceinline__ float funmap(unsigned u) {
    unsigned b = (u & 0x80000000u) ? (u & 0x7fffffffu) : ~u;
    return __uint_as_float(b);
}
__device__ __forceinline__ void fma_row4(float wv, uint2 r,
                                         float& ax, float& ay, float& az, float& aw) {
    float2 f01 = __half22float2(*(__half2*)&r.x);
    float2 f23 = __half22float2(*(__half2*)&r.y);
    ax += wv * f01.x; ay += wv * f01.y; az += wv * f23.x; aw += wv * f23.y;
}
__device__ __forceinline__ void fma_row8(float wv, uint4 r, float* a) {
    float2 f0 = __half22float2(*(__half2*)&r.x);
    float2 f1 = __half22float2(*(__half2*)&r.y);
    float2 f2 = __half22float2(*(__half2*)&r.z);
    float2 f3 = __half22float2(*(__half2*)&r.w);
    a[0] += wv * f0.x; a[1] += wv * f0.y;
    a[2] += wv * f1.x; a[3] += wv * f1.y;
    a[4] += wv * f2.x; a[5] += wv * f2.y;
    a[6] += wv * f3.x; a[7] += wv * f3.y;
}
__device__ __forceinline__ uint2 pack4(float ax, float ay, float az, float aw) {
    __half2 p01 = __float22half2_rn(make_float2(ax, ay));
    __half2 p23 = __float22half2_rn(make_float2(az, aw));
    uint2 r;
    r.x = *(unsigned*)&p01;
    r.y = *(unsigned*)&p23;
    return r;
}
__device__ __forceinline__ uint4 pack8(const float* a) {
    __half2 h0 = __float22half2_rn(make_float2(a[0], a[1]));
    __half2 h1 = __float22half2_rn(make_float2(a[2], a[3]));
    __half2 h2 = __float22half2_rn(make_float2(a[4], a[5]));
    __half2 h3 = __float22half2_rn(make_float2(a[6], a[7]));
    uint4 r;
    r.x = *(unsigned*)&h0; r.y = *(unsigned*)&h1;
    r.z = *(unsigned*)&h2; r.w = *(unsigned*)&h3;
    return r;
}

// ---------- CSR build (no self edges; self handled directly in props) ----------
__global__ void k_count(const int* __restrict__ dst, int* __restrict__ deg, int E) {
    int e = blockIdx.x * 256 + threadIdx.x;
    if (e < E) atomicAdd(&deg[dst[e]], 1);
}

__global__ void k_dis(const int* __restrict__ deg, float* __restrict__ dis, int N) {
    int i = blockIdx.x * 256 + threadIdx.x;
    if (i < N) dis[i] = rsqrtf((float)(deg[i] + 1));   // +1 = self loop
}

__global__ void k_scanA(const int* __restrict__ deg, int* __restrict__ rowst,
                        int* __restrict__ bsum, int N) {
    __shared__ int s[256];
    int i = blockIdx.x * 256 + threadIdx.x;
    int v = (i < N) ? deg[i] : 0;
    s[threadIdx.x] = v;
    __syncthreads();
    for (int off = 1; off < 256; off <<= 1) {
        int t = (threadIdx.x >= off) ? s[threadIdx.x - off] : 0;
        __syncthreads();
        s[threadIdx.x] += t;
        __syncthreads();
    }
    if (i < N) rowst[i] = s[threadIdx.x] - v;
    if (threadIdx.x == 255) bsum[blockIdx.x] = s[255];
}

__global__ void k_scanB(int* __restrict__ bsum, int NB) {
    __shared__ int s[512];
    int t = threadIdx.x;
    int v = (t < NB) ? bsum[t] : 0;
    s[t] = v;
    __syncthreads();
    for (int off = 1; off < 512; off <<= 1) {
        int x = (t >= off) ? s[t - off] : 0;
        __syncthreads();
        s[t] += x;
        __syncthreads();
    }
    if (t < NB) bsum[t] = s[t] - v;
}

__global__ void k_scanC(int* __restrict__ rowst, const int* __restrict__ bsum, int N) {
    int i = blockIdx.x * 256 + threadIdx.x;
    if (i < N) rowst[i] += bsum[blockIdx.x];
}

__global__ void k_fill(const int* __restrict__ src, const int* __restrict__ dst,
                       const float* __restrict__ dis, const int* __restrict__ rowst,
                       int* __restrict__ cnt, int2* __restrict__ edge, int E) {
    int e = blockIdx.x * 256 + threadIdx.x;
    if (e >= E) return;
    int d = dst[e], s = src[e];
    int p = rowst[d] + atomicAdd(&cnt[d], 1);
    edge[p] = make_int2(s, __float_as_int(dis[s] * dis[d]));
}

// ---------- x -> fp16 ----------
__global__ void k_x2h(const float* __restrict__ x, __half* __restrict__ xh, int n4) {
    int i = blockIdx.x * 256 + threadIdx.x;
    if (i >= n4) return;
    float4 v = ((const float4*)x)[i];
    ((uint2*)xh)[i] = pack4(v.x, v.y, v.z, v.w);
}

// ---------- prop16: p0 = prop(x) dim16 (fp16 rows, fp32 out); 4 lanes/node ----------
__global__ __launch_bounds__(256) void k_prop16(
        const __half* __restrict__ xh, float* __restrict__ out,
        const int* __restrict__ rowst, const int* __restrict__ deg,
        const int2* __restrict__ edge, int N) {
    int t = threadIdx.x, lane = t & 63, w = t >> 6;
    int grp = lane >> 2, sub = lane & 3;
    int node = blockIdx.x * 64 + w * 16 + grp;
    if (node >= N) return;
    const uint2* xr = (const uint2*)xh;        // row = 4 uint2 (32 B)
    int s = rowst[node], d = deg[node];
    float sc = 1.0f / (float)(d + 1);          // dis^2 self weight
    float ax = 0.f, ay = 0.f, az = 0.f, aw = 0.f;
    fma_row4(sc, xr[(size_t)node * 4 + sub], ax, ay, az, aw);
    const int2* ep = edge + s;
    for (int i = 0; i < d; i += 4) {
        int j1 = i + 1, j2 = i + 2, j3 = i + 3;
        int2 e0 = ep[i];
        int2 e1 = ep[(j1 < d) ? j1 : 0];
        int2 e2 = ep[(j2 < d) ? j2 : 0];
        int2 e3 = ep[(j3 < d) ? j3 : 0];
        uint2 r0 = xr[(size_t)e0.x * 4 + sub];
        uint2 r1 = xr[(size_t)e1.x * 4 + sub];
        uint2 r2 = xr[(size_t)e2.x * 4 + sub];
        uint2 r3 = xr[(size_t)e3.x * 4 + sub];
        float w0 = __int_as_float(e0.y);
        float w1 = (j1 < d) ? __int_as_float(e1.y) : 0.f;
        float w2 = (j2 < d) ? __int_as_float(e2.y) : 0.f;
        float w3 = (j3 < d) ? __int_as_float(e3.y) : 0.f;
        fma_row4(w0, r0, ax, ay, az, aw);
        fma_row4(w1, r1, ax, ay, az, aw);
        fma_row4(w2, r2, ax, ay, az, aw);
        fma_row4(w3, r3, ax, ay, az, aw);
    }
    ((float4*)out)[(size_t)node * 4 + sub] = make_float4(ax, ay, az, aw);
}

// ---------- dense: y2 = relu(p0@W1+b1)@W2 (fp32 in, fp16 out); wave per 4-node quad ----------
__global__ __launch_bounds__(256) void k_dense(
        const float* __restrict__ p0, __half* __restrict__ out,
        const float* __restrict__ W1, const float* __restrict__ b1,
        const float* __restrict__ W2, int N) {
    __shared__ float zT[4][128][4];
    int t = threadIdx.x, lane = t & 63, w = t >> 6;
    int base = (blockIdx.x * 4 + w) * 4;
    if (base >= N) return;
    float p = p0[(size_t)base * 16 + lane];
    float zA[4], zB[4];
    float bA = b1[lane], bB = b1[lane + 64];
    #pragma unroll
    for (int j = 0; j < 4; ++j) { zA[j] = bA; zB[j] = bB; }
    #pragma unroll
    for (int k = 0; k < 16; ++k) {
        float w1a = W1[k * 128 + lane];
        float w1b = W1[k * 128 + lane + 64];
        #pragma unroll
        for (int j = 0; j < 4; ++j) {
            float pk = __shfl(p, j * 16 + k);
            zA[j] += pk * w1a;
            zB[j] += pk * w1b;
        }
    }
    #pragma unroll
    for (int j = 0; j < 4; ++j) {
        zT[w][lane][j]      = fmaxf(zA[j], 0.f);
        zT[w][lane + 64][j] = fmaxf(zB[j], 0.f);
    }
    float acc[4] = {0.f, 0.f, 0.f, 0.f};
    #pragma unroll 4
    for (int k = 0; k < 128; ++k) {
        float wk = W2[k * 64 + lane];
        float4 zk = *(const float4*)&zT[w][k][0];
        acc[0] += zk.x * wk; acc[1] += zk.y * wk;
        acc[2] += zk.z * wk; acc[3] += zk.w * wk;
    }
    #pragma unroll
    for (int j = 0; j < 4; ++j)
        if (base + j < N) out[(size_t)(base + j) * 64 + lane] = __float2half(acc[j]);
}

// ---------- prop64: 2 nodes/wave, 8 edge-groups x 8 lanes x 16B ----------
// z = prop(in)+bias [relu]; out = HASW ? z@W(+gbias) : z
// dynamic LDS: HASW ? 10240 : 0
template<bool HASW>
__global__ __launch_bounds__(256) void k_prop64(
        const __half* __restrict__ in, __half* __restrict__ out,
        const int* __restrict__ rowst, const int* __restrict__ deg,
        const int2* __restrict__ edge,
        const float* __restrict__ bias, int relu,
        const float* __restrict__ W, const float* __restrict__ gbias, int N) {
    extern __shared__ char smem[];
    unsigned* Whl = (unsigned*)smem;              // [32][64] packed half2
    float* zb = (float*)(smem + 8192);            // [4][2][64]
    int t = threadIdx.x, lane = t & 63, w = t >> 6;
    int q = lane & 7, g = lane >> 3;              // 8 groups x 8 lanes (uint4)
    const uint4* inr = (const uint4*)in;          // row = 8 uint4 (128 B)
    if (HASW) {
        for (int i = t; i < 2048; i += 256) {
            int kk = i >> 6, l = i & 63;
            __half2 hh;
            hh.x = __float2half(W[(2 * kk) * 64 + l]);
            hh.y = __float2half(W[(2 * kk + 1) * 64 + l]);
            Whl[i] = *(unsigned*)&hh;
        }
        __syncthreads();
    }
    float b8[8] = {0.f, 0.f, 0.f, 0.f, 0.f, 0.f, 0.f, 0.f};
    if (bias) {
        float4 t0 = ((const float4*)bias)[q * 2];
        float4 t1 = ((const float4*)bias)[q * 2 + 1];
        b8[0] = t0.x; b8[1] = t0.y; b8[2] = t0.z; b8[3] = t0.w;
        b8[4] = t1.x; b8[5] = t1.y; b8[6] = t1.z; b8[7] = t1.w;
    }
    float gb = (HASW && gbias) ? gbias[lane] : 0.f;
    int wid = blockIdx.x * 4 + w;
    const int stride = gridDim.x * 4 * 2;
    for (int n0 = wid * 2; n0 < N; n0 += stride) {
        int n1 = n0 + 1;
        bool h1 = n1 < N;
        int s0 = rowst[n0], d0 = deg[n0];
        int s1 = h1 ? rowst[n1] : s0, d1 = h1 ? deg[n1] : 0;
        const int2* e0 = edge + s0;
        const int2* e1 = edge + s1;
        float a0[8] = {0,0,0,0,0,0,0,0};
        float a1[8] = {0,0,0,0,0,0,0,0};
        // self loops: weight dis^2 = 1/(deg+1), split over the 8 groups
        // (every group adds it; the xor-reduce sums 8 copies -> scale by 1/8)
        fma_row8(0.125f / (float)(d0 + 1), inr[(size_t)n0 * 8 + q], a0);
        fma_row8(h1 ? 0.125f / (float)(d1 + 1) : 0.f,
                 inr[(size_t)(h1 ? n1 : n0) * 8 + q], a1);
        int m = d0 > d1 ? d0 : d1;
        for (int base = 0; base < m; base += 16) {
            int i0 = base + g, i1 = base + g + 8;
            int2 ma0 = e0[(i0 < d0) ? i0 : 0];
            int2 ma1 = e0[(i1 < d0) ? i1 : 0];
            int2 mb0 = e1[(i0 < d1) ? i0 : 0];
            int2 mb1 = e1[(i1 < d1) ? i1 : 0];
            uint4 ra0 = inr[(size_t)ma0.x * 8 + q];
            uint4 ra1 = inr[(size_t)ma1.x * 8 + q];
            uint4 rb0 = inr[(size_t)mb0.x * 8 + q];
            uint4 rb1 = inr[(size_t)mb1.x * 8 + q];
            float wa0 = (i0 < d0) ? __int_as_float(ma0.y) : 0.f;
            float wa1 = (i1 < d0) ? __int_as_float(ma1.y) : 0.f;
            float wb0 = (i0 < d1) ? __int_as_float(mb0.y) : 0.f;
            float wb1 = (i1 < d1) ? __int_as_float(mb1.y) : 0.f;
            fma_row8(wa0, ra0, a0);
            fma_row8(wa1, ra1, a0);
            fma_row8(wb0, rb0, a1);
            fma_row8(wb1, rb1, a1);
        }
        // reduce over 8 edge-groups: xor 8, 16, 32
        #pragma unroll
        for (int j = 0; j < 8; ++j) {
            a0[j] += __shfl_xor(a0[j], 8);
            a1[j] += __shfl_xor(a1[j], 8);
        }
        #pragma unroll
        for (int j = 0; j < 8; ++j) {
            a0[j] += __shfl_xor(a0[j], 16);
            a1[j] += __shfl_xor(a1[j], 16);
        }
        #pragma unroll
        for (int j = 0; j < 8; ++j) {
            a0[j] += __shfl_xor(a0[j], 32);
            a1[j] += __shfl_xor(a1[j], 32);
        }
        #pragma unroll
        for (int j = 0; j < 8; ++j) {
            a0[j] += b8[j];
            a1[j] += b8[j];
        }
        if (relu) {
            #pragma unroll
            for (int j = 0; j < 8; ++j) {
                a0[j] = fmaxf(a0[j], 0.f);
                a1[j] = fmaxf(a1[j], 0.f);
            }
        }
        if (!HASW) {
            if (g == 0) {
                ((uint4*)out)[(size_t)n0 * 8 + q] = pack8(a0);
                if (h1) ((uint4*)out)[(size_t)n1 * 8 + q] = pack8(a1);
            }
        } else {
            if (g == 0) {
                float* z0 = &zb[(w * 2 + 0) * 64 + q * 8];
                float* z1 = &zb[(w * 2 + 1) * 64 + q * 8];
                *(float4*)&z0[0] = make_float4(a0[0], a0[1], a0[2], a0[3]);
                *(float4*)&z0[4] = make_float4(a0[4], a0[5], a0[6], a0[7]);
                *(float4*)&z1[0] = make_float4(a1[0], a1[1], a1[2], a1[3]);
                *(float4*)&z1[4] = make_float4(a1[4], a1[5], a1[6], a1[7]);
            }
            // wave-local LDS RAW: in-order per wave
            float acc0 = gb, acc1 = gb;
            #pragma unroll 8
            for (int kk = 0; kk < 32; ++kk) {
                unsigned u = Whl[kk * 64 + lane];
                float2 wp = __half22float2(*(__half2*)&u);
                float2 z0 = *(float2*)&zb[(w * 2 + 0) * 64 + 2 * kk];
                float2 z1 = *(float2*)&zb[(w * 2 + 1) * 64 + 2 * kk];
                acc0 += z0.x * wp.x + z0.y * wp.y;
                acc1 += z1.x * wp.x + z1.y * wp.y;
            }
            out[(size_t)n0 * 64 + lane] = __float2half(acc0);
            if (h1) out[(size_t)n1 * 64 + lane] = __float2half(acc1);
        }
    }
}

// ---------- pooling + head ----------
__global__ void k_pool_init(unsigned* __restrict__ gmax) {
    gmax[blockIdx.x * 64 + threadIdx.x] = fmap(-INFINITY);
}

__global__ void k_pool(const __half* __restrict__ z, const int* __restrict__ batch,
                       unsigned* __restrict__ gmax, int N) {
    int f = threadIdx.x & 63, w = threadIdx.x >> 6;
    int base = (blockIdx.x * 4 + w) * 32;
    if (base >= N) return;
    int end = base + 32; if (end > N) end = N;
    int b0 = batch[base], b1 = batch[end - 1];
    if (b0 == b1) {
        float lmax = -INFINITY;
        for (int n = base; n < end; ++n)
            lmax = fmaxf(lmax, __half2float(z[(size_t)n * 64 + f]));
        atomicMax(&gmax[b0 * 64 + f], fmap(lmax));
    } else {
        int curb = b0; float lmax = -INFINITY;
        for (int n = base; n < end; ++n) {
            int b = batch[n];
            if (b != curb) {
                atomicMax(&gmax[curb * 64 + f], fmap(lmax));
                curb = b; lmax = -INFINITY;
            }
            lmax = fmaxf(lmax, __half2float(z[(size_t)n * 64 + f]));
        }
        atomicMax(&gmax[curb * 64 + f], fmap(lmax));
    }
}

__global__ void k_head(const unsigned* __restrict__ gmax,
                       const float* __restrict__ Wf1, const float* __restrict__ bf1,
                       const float* __restrict__ Wf2, const float* __restrict__ bf2,
                       const float* __restrict__ Wc, const float* __restrict__ bc,
                       const float* __restrict__ Wcb, const float* __restrict__ bcb,
                       float* __restrict__ out) {
    __shared__ float g[8][64], h1[8][32], h2[8][16];
    int t = threadIdx.x;
    for (int i = t; i < 512; i += 64) g[i >> 6][i & 63] = funmap(gmax[i]);
    __syncthreads();
    for (int i = t; i < 256; i += 64) {
        int r = i >> 5, c = i & 31;
        float a = bf1[c];
        for (int k = 0; k < 64; ++k) a += g[r][k] * Wf1[k * 32 + c];
        h1[r][c] = fmaxf(a, 0.f);
    }
    __syncthreads();
    for (int i = t; i < 128; i += 64) {
        int r = i >> 4, c = i & 15;
        float a = bf2[c];
        for (int k = 0; k < 32; ++k) a += h1[r][k] * Wf2[k * 16 + c];
        h2[r][c] = fmaxf(a, 0.f);
    }
    __syncthreads();
    if (t < 16) {
        int r = t & 7;
        bool comb = t >= 8;
        const float* W = comb ? Wcb : Wc;
        float a = comb ? bcb[0] : bc[0];
        for (int k = 0; k < 16; ++k) a += h2[r][k] * W[k];
        out[(comb ? 8 : 0) + r] = a;
    }
}

// ---------- launch ----------
extern "C" void kernel_launch(void* const* d_in, const int* in_sizes, int n_in,
                              void* d_out, int out_size, void* d_ws, size_t ws_size,
                              hipStream_t stream) {
    const float* x    = (const float*)d_in[0];
    const int*   ei   = (const int*)d_in[1];
    const int*   batch= (const int*)d_in[2];
    const float* W1   = (const float*)d_in[3];
    const float* b1   = (const float*)d_in[4];
    const float* W2   = (const float*)d_in[5];
    const float* b2   = (const float*)d_in[6];
    const float* Wg1  = (const float*)d_in[7];
    const float* bg1  = (const float*)d_in[8];
    const float* Wg2  = (const float*)d_in[9];
    const float* bg2  = (const float*)d_in[10];
    const float* Wg3  = (const float*)d_in[11];
    const float* bg3  = (const float*)d_in[12];
    const float* Wsg  = (const float*)d_in[13];
    const float* bsg  = (const float*)d_in[14];
    const float* Wf1  = (const float*)d_in[15];
    const float* bf1  = (const float*)d_in[16];
    const float* Wf2  = (const float*)d_in[17];
    const float* bf2  = (const float*)d_in[18];
    const float* Wc   = (const float*)d_in[19];
    const float* bc   = (const float*)d_in[20];
    const float* Wcb  = (const float*)d_in[21];
    const float* bcb  = (const float*)d_in[22];

    const int N = in_sizes[0] / 16;
    const int E = in_sizes[1] / 2;
    const int* esrc = ei;
    const int* edst = ei + E;

    char* ws = (char*)d_ws;
    auto alloc = [&](size_t bytes) -> char* {
        char* p = ws;
        ws += (bytes + 255) & ~(size_t)255;
        return p;
    };
    int*      deg   = (int*)alloc((size_t)N * 4);
    int*      cnt   = (int*)alloc((size_t)N * 4);
    int*      rowst = (int*)alloc((size_t)(N + 1) * 4);
    int*      bsum  = (int*)alloc(4096);
    float*    dis   = (float*)alloc((size_t)N * 4);
    int2*     edge  = (int2*)alloc((size_t)(E + 16) * 8);
    __half*   xh    = (__half*)alloc((size_t)N * 16 * 2);
    float*    p0    = (float*)alloc((size_t)N * 16 * 4);
    __half*   bufA  = (__half*)alloc((size_t)N * 64 * 2);
    __half*   bufB  = (__half*)alloc((size_t)N * 64 * 2);
    unsigned* gmax  = (unsigned*)alloc((size_t)G_GRAPHS * 64 * 4);

    hipMemsetAsync(deg, 0, (size_t)N * 4, stream);
    hipMemsetAsync(cnt, 0, (size_t)N * 4, stream);
    hipMemsetAsync(edge + E, 0, 16 * 8, stream);   // zero pad

    const int EB = (E + 255) / 256;
    const int NB = (N + 255) / 256;
    const int PB = 2048;
    const size_t SW = 10240;   // dynamic LDS for HASW props

    k_count<<<EB, 256, 0, stream>>>(edst, deg, E);
    k_dis<<<NB, 256, 0, stream>>>(deg, dis, N);
    k_scanA<<<NB, 256, 0, stream>>>(deg, rowst, bsum, N);
    k_scanB<<<1, 512, 0, stream>>>(bsum, NB);
    k_scanC<<<NB, 256, 0, stream>>>(rowst, bsum, N);
    k_fill<<<EB, 256, 0, stream>>>(esrc, edst, dis, rowst, cnt, edge, E);
    k_x2h<<<(N * 4 + 255) / 256, 256, 0, stream>>>(x, xh, N * 4);

    // encoder: p0 = prop(x); y2 = relu(p0@W1+b1)@W2
    k_prop16<<<(N + 63) / 64, 256, 0, stream>>>(xh, p0, rowst, deg, edge, N);
    k_dense<<<(N + 15) / 16, 256, 0, stream>>>(p0, bufA, W1, b1, W2, N);
    // z2 = prop(y2)+b2 ; out = z2@Wg1
    k_prop64<true><<<PB, 256, SW, stream>>>(bufA, bufB, rowst, deg, edge, b2, 0, Wg1, nullptr, N);
    // z3 = relu(prop(.)+bg1) ; out = z3@Wg2
    k_prop64<true><<<PB, 256, SW, stream>>>(bufB, bufA, rowst, deg, edge, bg1, 1, Wg2, nullptr, N);
    // z4 = relu(prop(.)+bg2) ; out = z4@Wg3
    k_prop64<true><<<PB, 256, SW, stream>>>(bufA, bufB, rowst, deg, edge, bg2, 1, Wg3, nullptr, N);
    // z5 = relu(prop(.)+bg3)
    k_prop64<false><<<PB, 256, 0, stream>>>(bufB, bufA, rowst, deg, edge, bg3, 1, nullptr, nullptr, N);
    // SGConv: 3 plain props, then prop + @Wsg + bsg
    k_prop64<false><<<PB, 256, 0, stream>>>(bufA, bufB, rowst, deg, edge, nullptr, 0, nullptr, nullptr, N);
    k_prop64<false><<<PB, 256, 0, stream>>>(bufB, bufA, rowst, deg, edge, nullptr, 0, nullptr, nullptr, N);
    k_prop64<false><<<PB, 256, 0, stream>>>(bufA, bufB, rowst, deg, edge, nullptr, 0, nullptr, nullptr, N);
    k_prop64<true><<<PB, 256, SW, stream>>>(bufB, bufA, rowst, deg, edge, nullptr, 0, Wsg, bsg, N);

    // pool + head
    k_pool_init<<<G_GRAPHS, 64, 0, stream>>>(gmax);
    k_pool<<<(N + 127) / 128, 256, 0, stream>>>(bufA, batch, gmax, N);
    k_head<<<1, 64, 0, stream>>>(gmax, Wf1, bf1, Wf2, bf2, Wc, bc, Wcb, bcb, (float*)d_out);
}

// Round 13
// 628.636 us; speedup vs baseline: 1.5017x; 1.0543x over previous
//
#include <hip/hip_runtime.h>
#include <hip/hip_fp16.h>
#include <math.h>

#define G_GRAPHS 8

// ---------- helpers ----------
__device__ __forceinline__ unsigned fmap(float f) {
    unsigned b = __float_as_uint(f);
    return (b & 0x80000000u) ? ~b : (b | 0x80000000u);
}
__device__ __forceinline__ float funmap(unsigned u) {
    unsigned b = (u & 0x80000000u) ? (u & 0x7fffffffu) : ~u;
    return __uint_as_float(b);
}
__device__ __forceinline__ void fma_row4(float wv, uint2 r,
                                         float& ax, float& ay, float& az, float& aw) {
    float2 f01 = __half22float2(*(__half2*)&r.x);
    float2 f23 = __half22float2(*(__half2*)&r.y);
    ax += wv * f01.x; ay += wv * f01.y; az += wv * f23.x; aw += wv * f23.y;
}
__device__ __forceinline__ uint2 pack4(float ax, float ay, float az, float aw) {
    __half2 p01 = __float22half2_rn(make_float2(ax, ay));
    __half2 p23 = __float22half2_rn(make_float2(az, aw));
    uint2 r;
    r.x = *(unsigned*)&p01;
    r.y = *(unsigned*)&p23;
    return r;
}

// ---------- CSR build (no self edges; self handled directly in props) ----------
__global__ void k_count(const int* __restrict__ dst, int* __restrict__ deg, int E) {
    int e = blockIdx.x * 256 + threadIdx.x;
    if (e < E) atomicAdd(&deg[dst[e]], 1);
}

__global__ void k_dis(const int* __restrict__ deg, float* __restrict__ dis, int N) {
    int i = blockIdx.x * 256 + threadIdx.x;
    if (i < N) dis[i] = rsqrtf((float)(deg[i] + 1));   // +1 = self loop
}

__global__ void k_scanA(const int* __restrict__ deg, int* __restrict__ rowst,
                        int* __restrict__ bsum, int N) {
    __shared__ int s[256];
    int i = blockIdx.x * 256 + threadIdx.x;
    int v = (i < N) ? deg[i] : 0;
    s[threadIdx.x] = v;
    __syncthreads();
    for (int off = 1; off < 256; off <<= 1) {
        int t = (threadIdx.x >= off) ? s[threadIdx.x - off] : 0;
        __syncthreads();
        s[threadIdx.x] += t;
        __syncthreads();
    }
    if (i < N) rowst[i] = s[threadIdx.x] - v;
    if (threadIdx.x == 255) bsum[blockIdx.x] = s[255];
}

__global__ void k_scanB(int* __restrict__ bsum, int NB) {
    __shared__ int s[512];
    int t = threadIdx.x;
    int v = (t < NB) ? bsum[t] : 0;
    s[t] = v;
    __syncthreads();
    for (int off = 1; off < 512; off <<= 1) {
        int x = (t >= off) ? s[t - off] : 0;
        __syncthreads();
        s[t] += x;
        __syncthreads();
    }
    if (t < NB) bsum[t] = s[t] - v;
}

__global__ void k_scanC(int* __restrict__ rowst, const int* __restrict__ bsum, int N) {
    int i = blockIdx.x * 256 + threadIdx.x;
    if (i < N) rowst[i] += bsum[blockIdx.x];
}

__global__ void k_fill(const int* __restrict__ src, const int* __restrict__ dst,
                       const float* __restrict__ dis, const int* __restrict__ rowst,
                       int* __restrict__ cnt, int2* __restrict__ edge, int E) {
    int e = blockIdx.x * 256 + threadIdx.x;
    if (e >= E) return;
    int d = dst[e], s = src[e];
    int p = rowst[d] + atomicAdd(&cnt[d], 1);
    edge[p] = make_int2(s, __float_as_int(dis[s] * dis[d]));
}

// ---------- x -> fp16 ----------
__global__ void k_x2h(const float* __restrict__ x, __half* __restrict__ xh, int n4) {
    int i = blockIdx.x * 256 + threadIdx.x;
    if (i >= n4) return;
    float4 v = ((const float4*)x)[i];
    ((uint2*)xh)[i] = pack4(v.x, v.y, v.z, v.w);
}

// ---------- prop16: p0 = prop(x) dim16 (fp16 rows, fp32 out); 4 lanes/node ----------
__global__ __launch_bounds__(256) void k_prop16(
        const __half* __restrict__ xh, float* __restrict__ out,
        const int* __restrict__ rowst, const int* __restrict__ deg,
        const int2* __restrict__ edge, int N) {
    int t = threadIdx.x, lane = t & 63, w = t >> 6;
    int grp = lane >> 2, sub = lane & 3;
    int node = blockIdx.x * 64 + w * 16 + grp;
    if (node >= N) return;
    const uint2* xr = (const uint2*)xh;        // row = 4 uint2 (32 B)
    int s = rowst[node], d = deg[node];
    float sc = 1.0f / (float)(d + 1);          // dis^2 self weight
    float ax = 0.f, ay = 0.f, az = 0.f, aw = 0.f;
    fma_row4(sc, xr[(size_t)node * 4 + sub], ax, ay, az, aw);
    const int2* ep = edge + s;
    for (int i = 0; i < d; i += 4) {
        int j1 = i + 1, j2 = i + 2, j3 = i + 3;
        int2 e0 = ep[i];
        int2 e1 = ep[(j1 < d) ? j1 : 0];
        int2 e2 = ep[(j2 < d) ? j2 : 0];
        int2 e3 = ep[(j3 < d) ? j3 : 0];
        uint2 r0 = xr[(size_t)e0.x * 4 + sub];
        uint2 r1 = xr[(size_t)e1.x * 4 + sub];
        uint2 r2 = xr[(size_t)e2.x * 4 + sub];
        uint2 r3 = xr[(size_t)e3.x * 4 + sub];
        float w0 = __int_as_float(e0.y);
        float w1 = (j1 < d) ? __int_as_float(e1.y) : 0.f;
        float w2 = (j2 < d) ? __int_as_float(e2.y) : 0.f;
        float w3 = (j3 < d) ? __int_as_float(e3.y) : 0.f;
        fma_row4(w0, r0, ax, ay, az, aw);
        fma_row4(w1, r1, ax, ay, az, aw);
        fma_row4(w2, r2, ax, ay, az, aw);
        fma_row4(w3, r3, ax, ay, az, aw);
    }
    ((float4*)out)[(size_t)node * 4 + sub] = make_float4(ax, ay, az, aw);
}

// ---------- dense: y2 = relu(p0@W1+b1)@W2 (fp32 in, fp16 out); wave per 4-node quad ----------
__global__ __launch_bounds__(256) void k_dense(
        const float* __restrict__ p0, __half* __restrict__ out,
        const float* __restrict__ W1, const float* __restrict__ b1,
        const float* __restrict__ W2, int N) {
    __shared__ float zT[4][128][4];
    int t = threadIdx.x, lane = t & 63, w = t >> 6;
    int base = (blockIdx.x * 4 + w) * 4;
    if (base >= N) return;
    float p = p0[(size_t)base * 16 + lane];
    float zA[4], zB[4];
    float bA = b1[lane], bB = b1[lane + 64];
    #pragma unroll
    for (int j = 0; j < 4; ++j) { zA[j] = bA; zB[j] = bB; }
    #pragma unroll
    for (int k = 0; k < 16; ++k) {
        float w1a = W1[k * 128 + lane];
        float w1b = W1[k * 128 + lane + 64];
        #pragma unroll
        for (int j = 0; j < 4; ++j) {
            float pk = __shfl(p, j * 16 + k);
            zA[j] += pk * w1a;
            zB[j] += pk * w1b;
        }
    }
    #pragma unroll
    for (int j = 0; j < 4; ++j) {
        zT[w][lane][j]      = fmaxf(zA[j], 0.f);
        zT[w][lane + 64][j] = fmaxf(zB[j], 0.f);
    }
    float acc[4] = {0.f, 0.f, 0.f, 0.f};
    #pragma unroll 4
    for (int k = 0; k < 128; ++k) {
        float wk = W2[k * 64 + lane];
        float4 zk = *(const float4*)&zT[w][k][0];
        acc[0] += zk.x * wk; acc[1] += zk.y * wk;
        acc[2] += zk.z * wk; acc[3] += zk.w * wk;
    }
    #pragma unroll
    for (int j = 0; j < 4; ++j)
        if (base + j < N) out[(size_t)(base + j) * 64 + lane] = __float2half(acc[j]);
}

// ---------- prop64: 2 nodes/wave, 4 edge-groups x 16 lanes x 8B (r8 geometry) ----------
// z = prop(in)+bias [relu]; out = HASW ? z@W(+gbias) : z
// dynamic LDS: HASW ? 10240 : 0
template<bool HASW>
__global__ __launch_bounds__(256) void k_prop64(
        const __half* __restrict__ in, __half* __restrict__ out,
        const int* __restrict__ rowst, const int* __restrict__ deg,
        const int2* __restrict__ edge,
        const float* __restrict__ bias, int relu,
        const float* __restrict__ W, const float* __restrict__ gbias, int N) {
    extern __shared__ char smem[];
    unsigned* Whl = (unsigned*)smem;              // [32][64] packed half2
    float* zb = (float*)(smem + 8192);            // [4][2][64]
    int t = threadIdx.x, lane = t & 63, w = t >> 6;
    int q = lane & 15, g = lane >> 4;             // 4 edge-groups x 16 lanes (uint2)
    const uint2* inr = (const uint2*)in;          // row = 16 uint2 (128 B)
    if (HASW) {
        for (int i = t; i < 2048; i += 256) {
            int kk = i >> 6, l = i & 63;
            __half2 hh;
            hh.x = __float2half(W[(2 * kk) * 64 + l]);
            hh.y = __float2half(W[(2 * kk + 1) * 64 + l]);
            Whl[i] = *(unsigned*)&hh;
        }
        __syncthreads();
    }
    float4 b4 = make_float4(0.f, 0.f, 0.f, 0.f);
    if (bias) b4 = ((const float4*)bias)[q];
    float gb = (HASW && gbias) ? gbias[lane] : 0.f;
    int wid = blockIdx.x * 4 + w;
    const int stride = gridDim.x * 4 * 2;
    for (int n0 = wid * 2; n0 < N; n0 += stride) {
        int n1 = n0 + 1;
        bool h1 = n1 < N;
        int s0 = rowst[n0], d0 = deg[n0];
        int s1 = h1 ? rowst[n1] : s0, d1 = h1 ? deg[n1] : 0;
        const int2* e0 = edge + s0;
        const int2* e1 = edge + s1;
        float a0x = 0.f, a0y = 0.f, a0z = 0.f, a0w = 0.f;
        float a1x = 0.f, a1y = 0.f, a1z = 0.f, a1w = 0.f;
        // self loop: weight 1/(deg+1), each of the 4 groups adds -> scale 1/4
        fma_row4(0.25f / (float)(d0 + 1), inr[(size_t)n0 * 16 + q],
                 a0x, a0y, a0z, a0w);
        fma_row4(h1 ? 0.25f / (float)(d1 + 1) : 0.f,
                 inr[(size_t)(h1 ? n1 : n0) * 16 + q], a1x, a1y, a1z, a1w);
        int m = d0 > d1 ? d0 : d1;
        for (int base = 0; base < m; base += 16) {
            int i0 = base + g, i1 = i0 + 4, i2 = i0 + 8, i3 = i0 + 12;
            int2 ma0 = e0[(i0 < d0) ? i0 : 0];
            int2 ma1 = e0[(i1 < d0) ? i1 : 0];
            int2 ma2 = e0[(i2 < d0) ? i2 : 0];
            int2 ma3 = e0[(i3 < d0) ? i3 : 0];
            int2 mb0 = e1[(i0 < d1) ? i0 : 0];
            int2 mb1 = e1[(i1 < d1) ? i1 : 0];
            int2 mb2 = e1[(i2 < d1) ? i2 : 0];
            int2 mb3 = e1[(i3 < d1) ? i3 : 0];
            uint2 ra0 = inr[(size_t)ma0.x * 16 + q];
            uint2 ra1 = inr[(size_t)ma1.x * 16 + q];
            uint2 ra2 = inr[(size_t)ma2.x * 16 + q];
            uint2 ra3 = inr[(size_t)ma3.x * 16 + q];
            uint2 rb0 = inr[(size_t)mb0.x * 16 + q];
            uint2 rb1 = inr[(size_t)mb1.x * 16 + q];
            uint2 rb2 = inr[(size_t)mb2.x * 16 + q];
            uint2 rb3 = inr[(size_t)mb3.x * 16 + q];
            float wa0 = (i0 < d0) ? __int_as_float(ma0.y) : 0.f;
            float wa1 = (i1 < d0) ? __int_as_float(ma1.y) : 0.f;
            float wa2 = (i2 < d0) ? __int_as_float(ma2.y) : 0.f;
            float wa3 = (i3 < d0) ? __int_as_float(ma3.y) : 0.f;
            float wb0 = (i0 < d1) ? __int_as_float(mb0.y) : 0.f;
            float wb1 = (i1 < d1) ? __int_as_float(mb1.y) : 0.f;
            float wb2 = (i2 < d1) ? __int_as_float(mb2.y) : 0.f;
            float wb3 = (i3 < d1) ? __int_as_float(mb3.y) : 0.f;
            fma_row4(wa0, ra0, a0x, a0y, a0z, a0w);
            fma_row4(wa1, ra1, a0x, a0y, a0z, a0w);
            fma_row4(wa2, ra2, a0x, a0y, a0z, a0w);
            fma_row4(wa3, ra3, a0x, a0y, a0z, a0w);
            fma_row4(wb0, rb0, a1x, a1y, a1z, a1w);
            fma_row4(wb1, rb1, a1x, a1y, a1z, a1w);
            fma_row4(wb2, rb2, a1x, a1y, a1z, a1w);
            fma_row4(wb3, rb3, a1x, a1y, a1z, a1w);
        }
        // reduce the 4 edge-groups: xor 16, 32
        a0x += __shfl_xor(a0x,16); a0y += __shfl_xor(a0y,16); a0z += __shfl_xor(a0z,16); a0w += __shfl_xor(a0w,16);
        a0x += __shfl_xor(a0x,32); a0y += __shfl_xor(a0y,32); a0z += __shfl_xor(a0z,32); a0w += __shfl_xor(a0w,32);
        a1x += __shfl_xor(a1x,16); a1y += __shfl_xor(a1y,16); a1z += __shfl_xor(a1z,16); a1w += __shfl_xor(a1w,16);
        a1x += __shfl_xor(a1x,32); a1y += __shfl_xor(a1y,32); a1z += __shfl_xor(a1z,32); a1w += __shfl_xor(a1w,32);
        a0x += b4.x; a0y += b4.y; a0z += b4.z; a0w += b4.w;
        a1x += b4.x; a1y += b4.y; a1z += b4.z; a1w += b4.w;
        if (relu) {
            a0x = fmaxf(a0x,0.f); a0y = fmaxf(a0y,0.f); a0z = fmaxf(a0z,0.f); a0w = fmaxf(a0w,0.f);
            a1x = fmaxf(a1x,0.f); a1y = fmaxf(a1y,0.f); a1z = fmaxf(a1z,0.f); a1w = fmaxf(a1w,0.f);
        }
        if (!HASW) {
            if (g == 0) {
                ((uint2*)out)[(size_t)n0 * 16 + q] = pack4(a0x, a0y, a0z, a0w);
                if (h1) ((uint2*)out)[(size_t)n1 * 16 + q] = pack4(a1x, a1y, a1z, a1w);
            }
        } else {
            if (g == 0) {
                ((float4*)&zb[(w * 2 + 0) * 64])[q] = make_float4(a0x, a0y, a0z, a0w);
                ((float4*)&zb[(w * 2 + 1) * 64])[q] = make_float4(a1x, a1y, a1z, a1w);
            }
            // wave-local LDS RAW: in-order per wave
            float acc0 = gb, acc1 = gb;
            #pragma unroll 8
            for (int kk = 0; kk < 32; ++kk) {
                unsigned u = Whl[kk * 64 + lane];
                float2 wp = __half22float2(*(__half2*)&u);
                float2 z0 = *(float2*)&zb[(w * 2 + 0) * 64 + 2 * kk];
                float2 z1 = *(float2*)&zb[(w * 2 + 1) * 64 + 2 * kk];
                acc0 += z0.x * wp.x + z0.y * wp.y;
                acc1 += z1.x * wp.x + z1.y * wp.y;
            }
            out[(size_t)n0 * 64 + lane] = __float2half(acc0);
            if (h1) out[(size_t)n1 * 64 + lane] = __float2half(acc1);
        }
    }
}

// ---------- pooling + head ----------
__global__ void k_pool_init(unsigned* __restrict__ gmax) {
    gmax[blockIdx.x * 64 + threadIdx.x] = fmap(-INFINITY);
}

__global__ void k_pool(const __half* __restrict__ z, const int* __restrict__ batch,
                       unsigned* __restrict__ gmax, int N) {
    int f = threadIdx.x & 63, w = threadIdx.x >> 6;
    int base = (blockIdx.x * 4 + w) * 32;
    if (base >= N) return;
    int end = base + 32; if (end > N) end = N;
    int b0 = batch[base], b1 = batch[end - 1];
    if (b0 == b1) {
        float lmax = -INFINITY;
        for (int n = base; n < end; ++n)
            lmax = fmaxf(lmax, __half2float(z[(size_t)n * 64 + f]));
        atomicMax(&gmax[b0 * 64 + f], fmap(lmax));
    } else {
        int curb = b0; float lmax = -INFINITY;
        for (int n = base; n < end; ++n) {
            int b = batch[n];
            if (b != curb) {
                atomicMax(&gmax[curb * 64 + f], fmap(lmax));
                curb = b; lmax = -INFINITY;
            }
            lmax = fmaxf(lmax, __half2float(z[(size_t)n * 64 + f]));
        }
        atomicMax(&gmax[curb * 64 + f], fmap(lmax));
    }
}

__global__ void k_head(const unsigned* __restrict__ gmax,
                       const float* __restrict__ Wf1, const float* __restrict__ bf1,
                       const float* __restrict__ Wf2, const float* __restrict__ bf2,
                       const float* __restrict__ Wc, const float* __restrict__ bc,
                       const float* __restrict__ Wcb, const float* __restrict__ bcb,
                       float* __restrict__ out) {
    __shared__ float g[8][64], h1[8][32], h2[8][16];
    int t = threadIdx.x;
    for (int i = t; i < 512; i += 64) g[i >> 6][i & 63] = funmap(gmax[i]);
    __syncthreads();
    for (int i = t; i < 256; i += 64) {
        int r = i >> 5, c = i & 31;
        float a = bf1[c];
        for (int k = 0; k < 64; ++k) a += g[r][k] * Wf1[k * 32 + c];
        h1[r][c] = fmaxf(a, 0.f);
    }
    __syncthreads();
    for (int i = t; i < 128; i += 64) {
        int r = i >> 4, c = i & 15;
        float a = bf2[c];
        for (int k = 0; k < 32; ++k) a += h1[r][k] * Wf2[k * 16 + c];
        h2[r][c] = fmaxf(a, 0.f);
    }
    __syncthreads();
    if (t < 16) {
        int r = t & 7;
        bool comb = t >= 8;
        const float* W = comb ? Wcb : Wc;
        float a = comb ? bcb[0] : bc[0];
        for (int k = 0; k < 16; ++k) a += h2[r][k] * W[k];
        out[(comb ? 8 : 0) + r] = a;
    }
}

// ---------- launch ----------
extern "C" void kernel_launch(void* const* d_in, const int* in_sizes, int n_in,
                              void* d_out, int out_size, void* d_ws, size_t ws_size,
                              hipStream_t stream) {
    const float* x    = (const float*)d_in[0];
    const int*   ei   = (const int*)d_in[1];
    const int*   batch= (const int*)d_in[2];
    const float* W1   = (const float*)d_in[3];
    const float* b1   = (const float*)d_in[4];
    const float* W2   = (const float*)d_in[5];
    const float* b2   = (const float*)d_in[6];
    const float* Wg1  = (const float*)d_in[7];
    const float* bg1  = (const float*)d_in[8];
    const float* Wg2  = (const float*)d_in[9];
    const float* bg2  = (const float*)d_in[10];
    const float* Wg3  = (const float*)d_in[11];
    const float* bg3  = (const float*)d_in[12];
    const float* Wsg  = (const float*)d_in[13];
    const float* bsg  = (const float*)d_in[14];
    const float* Wf1  = (const float*)d_in[15];
    const float* bf1  = (const float*)d_in[16];
    const float* Wf2  = (const float*)d_in[17];
    const float* bf2  = (const float*)d_in[18];
    const float* Wc   = (const float*)d_in[19];
    const float* bc   = (const float*)d_in[20];
    const float* Wcb  = (const float*)d_in[21];
    const float* bcb  = (const float*)d_in[22];

    const int N = in_sizes[0] / 16;
    const int E = in_sizes[1] / 2;
    const int* esrc = ei;
    const int* edst = ei + E;

    char* ws = (char*)d_ws;
    auto alloc = [&](size_t bytes) -> char* {
        char* p = ws;
        ws += (bytes + 255) & ~(size_t)255;
        return p;
    };
    int*      deg   = (int*)alloc((size_t)N * 4);
    int*      cnt   = (int*)alloc((size_t)N * 4);
    int*      rowst = (int*)alloc((size_t)(N + 1) * 4);
    int*      bsum  = (int*)alloc(4096);
    float*    dis   = (float*)alloc((size_t)N * 4);
    int2*     edge  = (int2*)alloc((size_t)(E + 16) * 8);
    __half*   xh    = (__half*)alloc((size_t)N * 16 * 2);
    float*    p0    = (float*)alloc((size_t)N * 16 * 4);
    __half*   bufA  = (__half*)alloc((size_t)N * 64 * 2);
    __half*   bufB  = (__half*)alloc((size_t)N * 64 * 2);
    unsigned* gmax  = (unsigned*)alloc((size_t)G_GRAPHS * 64 * 4);

    hipMemsetAsync(deg, 0, (size_t)N * 4, stream);
    hipMemsetAsync(cnt, 0, (size_t)N * 4, stream);
    hipMemsetAsync(edge + E, 0, 16 * 8, stream);   // zero pad

    const int EB = (E + 255) / 256;
    const int NB = (N + 255) / 256;
    const int PB = 2048;
    const size_t SW = 10240;   // dynamic LDS for HASW props

    k_count<<<EB, 256, 0, stream>>>(edst, deg, E);
    k_dis<<<NB, 256, 0, stream>>>(deg, dis, N);
    k_scanA<<<NB, 256, 0, stream>>>(deg, rowst, bsum, N);
    k_scanB<<<1, 512, 0, stream>>>(bsum, NB);
    k_scanC<<<NB, 256, 0, stream>>>(rowst, bsum, N);
    k_fill<<<EB, 256, 0, stream>>>(esrc, edst, dis, rowst, cnt, edge, E);
    k_x2h<<<(N * 4 + 255) / 256, 256, 0, stream>>>(x, xh, N * 4);

    // encoder: p0 = prop(x); y2 = relu(p0@W1+b1)@W2
    k_prop16<<<(N + 63) / 64, 256, 0, stream>>>(xh, p0, rowst, deg, edge, N);
    k_dense<<<(N + 15) / 16, 256, 0, stream>>>(p0, bufA, W1, b1, W2, N);
    // z2 = prop(y2)+b2 ; out = z2@Wg1
    k_prop64<true><<<PB, 256, SW, stream>>>(bufA, bufB, rowst, deg, edge, b2, 0, Wg1, nullptr, N);
    // z3 = relu(prop(.)+bg1) ; out = z3@Wg2
    k_prop64<true><<<PB, 256, SW, stream>>>(bufB, bufA, rowst, deg, edge, bg1, 1, Wg2, nullptr, N);
    // z4 = relu(prop(.)+bg2) ; out = z4@Wg3
    k_prop64<true><<<PB, 256, SW, stream>>>(bufA, bufB, rowst, deg, edge, bg2, 1, Wg3, nullptr, N);
    // z5 = relu(prop(.)+bg3)
    k_prop64<false><<<PB, 256, 0, stream>>>(bufB, bufA, rowst, deg, edge, bg3, 1, nullptr, nullptr, N);
    // SGConv: 3 plain props, then prop + @Wsg + bsg
    k_prop64<false><<<PB, 256, 0, stream>>>(bufA, bufB, rowst, deg, edge, nullptr, 0, nullptr, nullptr, N);
    k_prop64<false><<<PB, 256, 0, stream>>>(bufB, bufA, rowst, deg, edge, nullptr, 0, nullptr, nullptr, N);
    k_prop64<false><<<PB, 256, 0, stream>>>(bufA, bufB, rowst, deg, edge, nullptr, 0, nullptr, nullptr, N);
    k_prop64<true><<<PB, 256, SW, stream>>>(bufB, bufA, rowst, deg, edge, nullptr, 0, Wsg, bsg, N);

    // pool + head
    k_pool_init<<<G_GRAPHS, 64, 0, stream>>>(gmax);
    k_pool<<<(N + 127) / 128, 256, 0, stream>>>(bufA, batch, gmax, N);
    k_head<<<1, 64, 0, stream>>>(gmax, Wf1, bf1, Wf2, bf2, Wc, bc, Wcb, bcb, (float*)d_out);
}

// Round 14
// 609.764 us; speedup vs baseline: 1.5482x; 1.0309x over previous
//
#include <hip/hip_runtime.h>
#include <hip/hip_bf16.h>
#include <hip/hip_fp16.h>
#include <math.h>

#define G_GRAPHS 8

// ---------- helpers ----------
__device__ __forceinline__ unsigned fmap(float f) {
    unsigned b = __float_as_uint(f);
    return (b & 0x80000000u) ? ~b : (b | 0x80000000u);
}
__device__ __forceinline__ float funmap(unsigned u) {
    unsigned b = (u & 0x80000000u) ? (u & 0x7fffffffu) : ~u;
    return __uint_as_float(b);
}
__device__ __forceinline__ void fma_row(float wv, uint2 r,
                                        float& ax, float& ay, float& az, float& aw) {
    float2 f01 = __half22float2(*(__half2*)&r.x);
    float2 f23 = __half22float2(*(__half2*)&r.y);
    ax += wv * f01.x; ay += wv * f01.y; az += wv * f23.x; aw += wv * f23.y;
}
__device__ __forceinline__ uint2 pack4(float ax, float ay, float az, float aw) {
    __half2 p01 = __float22half2_rn(make_float2(ax, ay));
    __half2 p23 = __float22half2_rn(make_float2(az, aw));
    uint2 r;
    r.x = *(unsigned*)&p01;
    r.y = *(unsigned*)&p23;
    return r;
}

// ---------- CSR build ----------
__global__ void k_count(const int* __restrict__ dst, int* __restrict__ deg, int E) {
    int e = blockIdx.x * 256 + threadIdx.x;
    if (e < E) atomicAdd(&deg[dst[e]], 1);
}

__global__ void k_dis(const int* __restrict__ deg, float* __restrict__ dis, int N) {
    int i = blockIdx.x * 256 + threadIdx.x;
    if (i < N) dis[i] = rsqrtf((float)(deg[i] + 1));  // +1 = self loop
}

__global__ void k_scanA(const int* __restrict__ deg, int* __restrict__ rowst,
                        int* __restrict__ bsum, int N) {
    __shared__ int s[256];
    int i = blockIdx.x * 256 + threadIdx.x;
    int v = (i < N) ? deg[i] : 0;
    s[threadIdx.x] = v;
    __syncthreads();
    for (int off = 1; off < 256; off <<= 1) {
        int t = (threadIdx.x >= off) ? s[threadIdx.x - off] : 0;
        __syncthreads();
        s[threadIdx.x] += t;
        __syncthreads();
    }
    if (i < N) rowst[i] = s[threadIdx.x] - v;   // block-local exclusive
    if (threadIdx.x == 255) bsum[blockIdx.x] = s[255];
}

__global__ void k_scanB(int* __restrict__ bsum, int NB) {
    __shared__ int s[512];
    int t = threadIdx.x;
    int v = (t < NB) ? bsum[t] : 0;
    s[t] = v;
    __syncthreads();
    for (int off = 1; off < 512; off <<= 1) {
        int x = (t >= off) ? s[t - off] : 0;
        __syncthreads();
        s[t] += x;
        __syncthreads();
    }
    if (t < NB) bsum[t] = s[t] - v;             // exclusive
}

__global__ void k_scanC(int* __restrict__ rowst, const int* __restrict__ bsum, int N) {
    int i = blockIdx.x * 256 + threadIdx.x;
    if (i < N) rowst[i] += bsum[blockIdx.x];
}

__global__ void k_fill(const int* __restrict__ src, const int* __restrict__ dst,
                       const float* __restrict__ dis, const int* __restrict__ rowst,
                       int* __restrict__ cnt, int2* __restrict__ edge, int E) {
    int e = blockIdx.x * 256 + threadIdx.x;
    if (e >= E) return;
    int d = dst[e], s = src[e];
    int p = rowst[d] + atomicAdd(&cnt[d], 1);
    edge[p] = make_int2(s, __float_as_int(dis[s] * dis[d]));
}

// ---------- x -> fp16 copy ----------
__global__ void k_x2h(const float* __restrict__ x, __half* __restrict__ xh, int n4) {
    int i = blockIdx.x * 256 + threadIdx.x;   // one float4 per thread
    if (i >= n4) return;
    float4 v = ((const float4*)x)[i];
    ((uint2*)xh)[i] = pack4(v.x, v.y, v.z, v.w);
}

// ---------- prop16: p0 = prop(x) dim16 (fp16 rows, fp32 out); 4 lanes/node ----------
__global__ __launch_bounds__(256) void k_prop16(
        const __half* __restrict__ xh, float* __restrict__ out,
        const float* __restrict__ dis, const int* __restrict__ rowst,
        const int* __restrict__ deg, const int2* __restrict__ edge, int N) {
    int t = threadIdx.x, lane = t & 63, w = t >> 6;
    int grp = lane >> 2, sub = lane & 3;
    int node = blockIdx.x * 64 + w * 16 + grp;
    if (node >= N) return;
    const uint2* xr = (const uint2*)xh;        // row = 4 uint2 (32 B)
    float d = dis[node];
    float sc = d * d;
    float ax = 0.f, ay = 0.f, az = 0.f, aw = 0.f;
    fma_row(sc, xr[node * 4 + sub], ax, ay, az, aw);
    int s = rowst[node], dg = deg[node];
    const int2* ep = edge + s;
    int i = 0;
    for (; i + 3 < dg; i += 4) {
        int2 e0 = ep[i], e1 = ep[i + 1], e2 = ep[i + 2], e3 = ep[i + 3];
        uint2 r0 = xr[e0.x * 4 + sub];
        uint2 r1 = xr[e1.x * 4 + sub];
        uint2 r2 = xr[e2.x * 4 + sub];
        uint2 r3 = xr[e3.x * 4 + sub];
        fma_row(__int_as_float(e0.y), r0, ax, ay, az, aw);
        fma_row(__int_as_float(e1.y), r1, ax, ay, az, aw);
        fma_row(__int_as_float(e2.y), r2, ax, ay, az, aw);
        fma_row(__int_as_float(e3.y), r3, ax, ay, az, aw);
    }
    for (; i < dg; ++i) {
        int2 e0 = ep[i];
        fma_row(__int_as_float(e0.y), xr[e0.x * 4 + sub], ax, ay, az, aw);
    }
    ((float4*)out)[node * 4 + sub] = make_float4(ax, ay, az, aw);
}

// ---------- dense: y2 = relu(p0@W1+b1)@W2 (fp32 in, fp16 out); wave per 4-node quad ----------
__global__ __launch_bounds__(256) void k_dense(
        const float* __restrict__ p0, __half* __restrict__ out,
        const float* __restrict__ W1, const float* __restrict__ b1,
        const float* __restrict__ W2, int N) {
    __shared__ float zT[4][128][4];   // [wave][feat][node-in-quad]
    int t = threadIdx.x, lane = t & 63, w = t >> 6;
    int base = (blockIdx.x * 4 + w) * 4;   // first node of quad
    if (base >= N) return;
    // lane L holds p0[node base+(L>>4)][feat L&15]
    float p = p0[base * 16 + lane];
    float zA[4], zB[4];
    float bA = b1[lane], bB = b1[lane + 64];
    #pragma unroll
    for (int j = 0; j < 4; ++j) { zA[j] = bA; zB[j] = bB; }
    #pragma unroll
    for (int k = 0; k < 16; ++k) {
        float w1a = W1[k * 128 + lane];
        float w1b = W1[k * 128 + lane + 64];
        #pragma unroll
        for (int j = 0; j < 4; ++j) {
            float pk = __shfl(p, j * 16 + k);
            zA[j] += pk * w1a;
            zB[j] += pk * w1b;
        }
    }
    #pragma unroll
    for (int j = 0; j < 4; ++j) {
        zT[w][lane][j]      = fmaxf(zA[j], 0.f);
        zT[w][lane + 64][j] = fmaxf(zB[j], 0.f);
    }
    // wave-local LDS RAW; in-order per wave
    float acc[4] = {0.f, 0.f, 0.f, 0.f};
    #pragma unroll 4
    for (int k = 0; k < 128; ++k) {
        float wk = W2[k * 64 + lane];
        float4 zk = *(const float4*)&zT[w][k][0];
        acc[0] += zk.x * wk; acc[1] += zk.y * wk;
        acc[2] += zk.z * wk; acc[3] += zk.w * wk;
    }
    #pragma unroll
    for (int j = 0; j < 4; ++j)
        if (base + j < N) out[(base + j) * 64 + lane] = __float2half(acc[j]);
}

// ---------- prop64 (persistent, 2 nodes/wave, fp16 rows): z = prop(in)+bias [relu]; out = W ? z@W(+gbias) : z
__global__ __launch_bounds__(256) void k_prop64(
        const __half* __restrict__ in, __half* __restrict__ out,
        const float* __restrict__ dis, const int* __restrict__ rowst,
        const int* __restrict__ deg, const int2* __restrict__ edge,
        const float* __restrict__ bias, int relu,
        const float* __restrict__ W, const float* __restrict__ gbias, int N) {
    __shared__ float Wlds[64 * 64];
    __shared__ float zbuf[4][2][64];
    int t = threadIdx.x, lane = t & 63, w = t >> 6;
    int q = lane & 15, g = lane >> 4;          // 4 edge groups x 16 lanes (uint2)
    const uint2* inr = (const uint2*)in;       // row = 16 uint2 (128 B)
    if (W) {
        for (int i = t; i < 64 * 64 / 4; i += 256)
            ((float4*)Wlds)[i] = ((const float4*)W)[i];
        __syncthreads();
    }
    float4 b4 = make_float4(0.f, 0.f, 0.f, 0.f);
    if (bias) b4 = ((const float4*)bias)[q];
    float gb = (W && gbias) ? gbias[lane] : 0.f;
    int wid = blockIdx.x * 4 + w;
    const int stride = gridDim.x * 4 * 2;
    for (int n0 = wid * 2; n0 < N; n0 += stride) {
        int n1 = n0 + 1;
        bool h1 = n1 < N;
        int s0 = rowst[n0], d0 = deg[n0];
        int s1 = h1 ? rowst[n1] : s0, d1 = h1 ? deg[n1] : 0;
        float di0 = dis[n0];
        float di1 = h1 ? dis[n1] : 0.f;
        const int2* e0 = edge + s0;
        const int2* e1 = edge + s1;
        float sc0 = di0 * di0 * 0.25f, sc1 = di1 * di1 * 0.25f;
        float a0x = 0.f, a0y = 0.f, a0z = 0.f, a0w = 0.f;
        float a1x = 0.f, a1y = 0.f, a1z = 0.f, a1w = 0.f;
        fma_row(sc0, inr[n0 * 16 + q], a0x, a0y, a0z, a0w);
        fma_row(sc1, inr[(h1 ? n1 : n0) * 16 + q], a1x, a1y, a1z, a1w);
        int m = d0 > d1 ? d0 : d1;
        for (int base = 0; base < m; base += 16) {
            int i0 = base + g, i1 = i0 + 4, i2 = i0 + 8, i3 = i0 + 12;
            // node 0: 4 edges
            int2 ma0 = e0[(i0 < d0) ? i0 : 0];
            int2 ma1 = e0[(i1 < d0) ? i1 : 0];
            int2 ma2 = e0[(i2 < d0) ? i2 : 0];
            int2 ma3 = e0[(i3 < d0) ? i3 : 0];
            // node 1: 4 edges
            int2 mb0 = e1[(i0 < d1) ? i0 : 0];
            int2 mb1 = e1[(i1 < d1) ? i1 : 0];
            int2 mb2 = e1[(i2 < d1) ? i2 : 0];
            int2 mb3 = e1[(i3 < d1) ? i3 : 0];
            uint2 ra0 = inr[ma0.x * 16 + q];
            uint2 ra1 = inr[ma1.x * 16 + q];
            uint2 ra2 = inr[ma2.x * 16 + q];
            uint2 ra3 = inr[ma3.x * 16 + q];
            uint2 rb0 = inr[mb0.x * 16 + q];
            uint2 rb1 = inr[mb1.x * 16 + q];
            uint2 rb2 = inr[mb2.x * 16 + q];
            uint2 rb3 = inr[mb3.x * 16 + q];
            float wa0 = (i0 < d0) ? __int_as_float(ma0.y) : 0.f;
            float wa1 = (i1 < d0) ? __int_as_float(ma1.y) : 0.f;
            float wa2 = (i2 < d0) ? __int_as_float(ma2.y) : 0.f;
            float wa3 = (i3 < d0) ? __int_as_float(ma3.y) : 0.f;
            float wb0 = (i0 < d1) ? __int_as_float(mb0.y) : 0.f;
            float wb1 = (i1 < d1) ? __int_as_float(mb1.y) : 0.f;
            float wb2 = (i2 < d1) ? __int_as_float(mb2.y) : 0.f;
            float wb3 = (i3 < d1) ? __int_as_float(mb3.y) : 0.f;
            fma_row(wa0, ra0, a0x, a0y, a0z, a0w);
            fma_row(wa1, ra1, a0x, a0y, a0z, a0w);
            fma_row(wa2, ra2, a0x, a0y, a0z, a0w);
            fma_row(wa3, ra3, a0x, a0y, a0z, a0w);
            fma_row(wb0, rb0, a1x, a1y, a1z, a1w);
            fma_row(wb1, rb1, a1x, a1y, a1z, a1w);
            fma_row(wb2, rb2, a1x, a1y, a1z, a1w);
            fma_row(wb3, rb3, a1x, a1y, a1z, a1w);
        }
        // reduce the 4 edge-groups: xor 16, 32
        a0x += __shfl_xor(a0x,16); a0y += __shfl_xor(a0y,16); a0z += __shfl_xor(a0z,16); a0w += __shfl_xor(a0w,16);
        a0x += __shfl_xor(a0x,32); a0y += __shfl_xor(a0y,32); a0z += __shfl_xor(a0z,32); a0w += __shfl_xor(a0w,32);
        a1x += __shfl_xor(a1x,16); a1y += __shfl_xor(a1y,16); a1z += __shfl_xor(a1z,16); a1w += __shfl_xor(a1w,16);
        a1x += __shfl_xor(a1x,32); a1y += __shfl_xor(a1y,32); a1z += __shfl_xor(a1z,32); a1w += __shfl_xor(a1w,32);
        a0x += b4.x; a0y += b4.y; a0z += b4.z; a0w += b4.w;
        a1x += b4.x; a1y += b4.y; a1z += b4.z; a1w += b4.w;
        if (relu) {
            a0x = fmaxf(a0x,0.f); a0y = fmaxf(a0y,0.f); a0z = fmaxf(a0z,0.f); a0w = fmaxf(a0w,0.f);
            a1x = fmaxf(a1x,0.f); a1y = fmaxf(a1y,0.f); a1z = fmaxf(a1z,0.f); a1w = fmaxf(a1w,0.f);
        }
        if (!W) {
            if (g == 0) {
                ((uint2*)out)[n0 * 16 + q] = pack4(a0x, a0y, a0z, a0w);
                if (h1) ((uint2*)out)[n1 * 16 + q] = pack4(a1x, a1y, a1z, a1w);
            }
        } else {
            if (g == 0) {
                ((float4*)zbuf[w][0])[q] = make_float4(a0x, a0y, a0z, a0w);
                ((float4*)zbuf[w][1])[q] = make_float4(a1x, a1y, a1z, a1w);
            }
            // wave-local LDS RAW: in-order per wave
            float acc0 = gb, acc1 = gb;
            for (int k = 0; k < 64; ++k) {
                float wk = Wlds[k * 64 + lane];
                acc0 += zbuf[w][0][k] * wk;
                acc1 += zbuf[w][1][k] * wk;
            }
            out[n0 * 64 + lane] = __float2half(acc0);
            if (h1) out[n1 * 64 + lane] = __float2half(acc1);
        }
    }
}

// ---------- pooling + head ----------
__global__ void k_pool_init(unsigned* __restrict__ gmax) {
    gmax[blockIdx.x * 64 + threadIdx.x] = fmap(-INFINITY);
}

__global__ void k_pool(const __half* __restrict__ z, const int* __restrict__ batch,
                       unsigned* __restrict__ gmax, int N) {
    int f = threadIdx.x & 63, w = threadIdx.x >> 6;
    int base = (blockIdx.x * 4 + w) * 32;
    if (base >= N) return;
    int end = base + 32; if (end > N) end = N;
    int b0 = batch[base], b1 = batch[end - 1];
    if (b0 == b1) {                            // fast path: single graph in window
        float lmax = -INFINITY;
        for (int n = base; n < end; ++n)
            lmax = fmaxf(lmax, __half2float(z[n * 64 + f]));
        atomicMax(&gmax[b0 * 64 + f], fmap(lmax));
    } else {
        int curb = b0; float lmax = -INFINITY;
        for (int n = base; n < end; ++n) {
            int b = batch[n];
            if (b != curb) {
                atomicMax(&gmax[curb * 64 + f], fmap(lmax));
                curb = b; lmax = -INFINITY;
            }
            lmax = fmaxf(lmax, __half2float(z[n * 64 + f]));
        }
        atomicMax(&gmax[curb * 64 + f], fmap(lmax));
    }
}

__global__ void k_head(const unsigned* __restrict__ gmax,
                       const float* __restrict__ Wf1, const float* __restrict__ bf1,
                       const float* __restrict__ Wf2, const float* __restrict__ bf2,
                       const float* __restrict__ Wc, const float* __restrict__ bc,
                       const float* __restrict__ Wcb, const float* __restrict__ bcb,
                       float* __restrict__ out) {
    __shared__ float g[8][64], h1[8][32], h2[8][16];
    int t = threadIdx.x;  // 64 threads
    for (int i = t; i < 512; i += 64) g[i >> 6][i & 63] = funmap(gmax[i]);
    __syncthreads();
    for (int i = t; i < 256; i += 64) {
        int r = i >> 5, c = i & 31;
        float a = bf1[c];
        for (int k = 0; k < 64; ++k) a += g[r][k] * Wf1[k * 32 + c];
        h1[r][c] = fmaxf(a, 0.f);
    }
    __syncthreads();
    for (int i = t; i < 128; i += 64) {
        int r = i >> 4, c = i & 15;
        float a = bf2[c];
        for (int k = 0; k < 32; ++k) a += h1[r][k] * Wf2[k * 16 + c];
        h2[r][c] = fmaxf(a, 0.f);
    }
    __syncthreads();
    if (t < 16) {
        int r = t & 7;
        bool comb = t >= 8;
        const float* W = comb ? Wcb : Wc;
        float a = comb ? bcb[0] : bc[0];
        for (int k = 0; k < 16; ++k) a += h2[r][k] * W[k];
        out[(comb ? 8 : 0) + r] = a;
    }
}

// ---------- launch ----------
extern "C" void kernel_launch(void* const* d_in, const int* in_sizes, int n_in,
                              void* d_out, int out_size, void* d_ws, size_t ws_size,
                              hipStream_t stream) {
    const float* x    = (const float*)d_in[0];
    const int*   ei   = (const int*)d_in[1];
    const int*   batch= (const int*)d_in[2];
    const float* W1   = (const float*)d_in[3];
    const float* b1   = (const float*)d_in[4];
    const float* W2   = (const float*)d_in[5];
    const float* b2   = (const float*)d_in[6];
    const float* Wg1  = (const float*)d_in[7];
    const float* bg1  = (const float*)d_in[8];
    const float* Wg2  = (const float*)d_in[9];
    const float* bg2  = (const float*)d_in[10];
    const float* Wg3  = (const float*)d_in[11];
    const float* bg3  = (const float*)d_in[12];
    const float* Wsg  = (const float*)d_in[13];
    const float* bsg  = (const float*)d_in[14];
    const float* Wf1  = (const float*)d_in[15];
    const float* bf1  = (const float*)d_in[16];
    const float* Wf2  = (const float*)d_in[17];
    const float* bf2  = (const float*)d_in[18];
    const float* Wc   = (const float*)d_in[19];
    const float* bc   = (const float*)d_in[20];
    const float* Wcb  = (const float*)d_in[21];
    const float* bcb  = (const float*)d_in[22];

    const int N = in_sizes[0] / 16;
    const int E = in_sizes[1] / 2;
    const int* esrc = ei;
    const int* edst = ei + E;

    char* ws = (char*)d_ws;
    auto alloc = [&](size_t bytes) -> char* {
        char* p = ws;
        ws += (bytes + 255) & ~(size_t)255;
        return p;
    };
    int*      deg   = (int*)alloc((size_t)N * 4);
    int*      cnt   = (int*)alloc((size_t)N * 4);
    int*      rowst = (int*)alloc((size_t)(N + 1) * 4);
    int*      bsum  = (int*)alloc(4096);
    float*    dis   = (float*)alloc((size_t)N * 4);
    int2*     edge  = (int2*)alloc((size_t)(E + 16) * 8);
    __half*   xh    = (__half*)alloc((size_t)N * 16 * 2);
    float*    p0    = (float*)alloc((size_t)N * 16 * 4);
    __half*   bufA  = (__half*)alloc((size_t)N * 64 * 2);
    __half*   bufB  = (__half*)alloc((size_t)N * 64 * 2);
    unsigned* gmax  = (unsigned*)alloc((size_t)G_GRAPHS * 64 * 4);

    hipMemsetAsync(deg, 0, (size_t)N * 4, stream);
    hipMemsetAsync(cnt, 0, (size_t)N * 4, stream);
    hipMemsetAsync(edge + E, 0, 16 * 8, stream);   // zero pad for clamped loads

    const int EB = (E + 255) / 256;
    const int NB = (N + 255) / 256;
    const int PB = 2048;   // persistent prop blocks

    k_count<<<EB, 256, 0, stream>>>(edst, deg, E);
    k_dis<<<NB, 256, 0, stream>>>(deg, dis, N);
    k_scanA<<<NB, 256, 0, stream>>>(deg, rowst, bsum, N);
    k_scanB<<<1, 512, 0, stream>>>(bsum, NB);
    k_scanC<<<NB, 256, 0, stream>>>(rowst, bsum, N);
    k_fill<<<EB, 256, 0, stream>>>(esrc, edst, dis, rowst, cnt, edge, E);
    k_x2h<<<(N * 4 + 255) / 256, 256, 0, stream>>>(x, xh, N * 4);

    // encoder: p0 = prop(x); y2 = relu(p0@W1+b1)@W2
    k_prop16<<<(N + 63) / 64, 256, 0, stream>>>(xh, p0, dis, rowst, deg, edge, N);
    k_dense<<<(N + 15) / 16, 256, 0, stream>>>(p0, bufA, W1, b1, W2, N);
    // z2 = prop(y2)+b2; out = z2@Wg1
    k_prop64<<<PB, 256, 0, stream>>>(bufA, bufB, dis, rowst, deg, edge, b2, 0, Wg1, nullptr, N);
    // z3 = relu(prop(.)+bg1); out = z3@Wg2
    k_prop64<<<PB, 256, 0, stream>>>(bufB, bufA, dis, rowst, deg, edge, bg1, 1, Wg2, nullptr, N);
    // z4 = relu(prop(.)+bg2); out = z4@Wg3
    k_prop64<<<PB, 256, 0, stream>>>(bufA, bufB, dis, rowst, deg, edge, bg2, 1, Wg3, nullptr, N);
    // z5 = relu(prop(.)+bg3)
    k_prop64<<<PB, 256, 0, stream>>>(bufB, bufA, dis, rowst, deg, edge, bg3, 1, nullptr, nullptr, N);
    // SGConv: 3 plain props, then prop + @Wsg + bsg
    k_prop64<<<PB, 256, 0, stream>>>(bufA, bufB, dis, rowst, deg, edge, nullptr, 0, nullptr, nullptr, N);
    k_prop64<<<PB, 256, 0, stream>>>(bufB, bufA, dis, rowst, deg, edge, nullptr, 0, nullptr, nullptr, N);
    k_prop64<<<PB, 256, 0, stream>>>(bufA, bufB, dis, rowst, deg, edge, nullptr, 0, nullptr, nullptr, N);
    k_prop64<<<PB, 256, 0, stream>>>(bufB, bufA, dis, rowst, deg, edge, nullptr, 0, Wsg, bsg, N);

    // pool + head
    k_pool_init<<<G_GRAPHS, 64, 0, stream>>>(gmax);
    k_pool<<<(N + 127) / 128, 256, 0, stream>>>(bufA, batch, gmax, N);
    k_head<<<1, 64, 0, stream>>>(gmax, Wf1, bf1, Wf2, bf2, Wc, bc, Wcb, bcb, (float*)d_out);
}